// Round 2
// baseline (973.029 us; speedup 1.0000x reference)
//
#include <hip/hip_runtime.h>
#include <stdint.h>

#define ALPHA 0.3f
#define CLAMPV 0.3f
#define BDIM 4096
#define NDIM 1024

typedef float f32x4 __attribute__((ext_vector_type(4)));
typedef __bf16 bf16x8 __attribute__((ext_vector_type(8)));

union U16x8 { uint4 v; unsigned short u[8]; };

__device__ __forceinline__ float bf2f(unsigned short u) {
  union { unsigned int i; float f; } c; c.i = ((unsigned int)u) << 16; return c.f;
}
__device__ __forceinline__ unsigned short f2bf(float f) {
  union { float f; unsigned int i; } c; c.f = f;
  unsigned int u = c.i;
  unsigned int r = u + 0x7FFFu + ((u >> 16) & 1u);
  return (unsigned short)(r >> 16);
}

// ---------------------------------------------------------------------------
// ws-too-small signal: fill output with a recognizable constant
// ---------------------------------------------------------------------------
__global__ __launch_bounds__(256) void fill_k(float* __restrict__ out, int n) {
  int i = blockIdx.x * 256 + threadIdx.x;
  if (i < n) out[i] = 12345.0f;
}

// ---------------------------------------------------------------------------
// split x (f32) -> bf16 hi/lo
// ---------------------------------------------------------------------------
__global__ __launch_bounds__(256) void split_x_k(const float* __restrict__ x,
                                                 unsigned short* __restrict__ hi,
                                                 unsigned short* __restrict__ lo) {
  const size_t i0 = ((size_t)blockIdx.x * 256 + threadIdx.x) * 8;
  f32x4 a = *(const f32x4*)(x + i0);
  f32x4 b = *(const f32x4*)(x + i0 + 4);
  U16x8 h8, l8;
#pragma unroll
  for (int i = 0; i < 4; ++i) {
    unsigned short h = f2bf(a[i]); h8.u[i] = h; l8.u[i] = f2bf(a[i] - bf2f(h));
    unsigned short h2 = f2bf(b[i]); h8.u[4+i] = h2; l8.u[4+i] = f2bf(b[i] - bf2f(h2));
  }
  *(uint4*)(hi + i0) = h8.v;
  *(uint4*)(lo + i0) = l8.v;
}

// ---------------------------------------------------------------------------
// batched tiled transpose: out[C][R] (bf16 hi / optional lo) from in[R][C]
// mode 0: bf16 in -> bf16 out (hi only, lossless)
// mode 1: f32 in  -> split hi/lo
// mode 2: (in1 + W*in2) f32 -> split hi/lo   (Weff prep)
// ---------------------------------------------------------------------------
struct TDesc {
  const void* in1; const void* in2; const float* Wp;
  unsigned short* out_hi; unsigned short* out_lo;
  int R, C, tilesC, mode;
};
struct TBatch { TDesc d[8]; int start[9]; int n; };

__global__ __launch_bounds__(256) void transpose_k(TBatch batch) {
  const int bid = blockIdx.x;
  int g = 0;
#pragma unroll
  for (int i = 1; i < 8; ++i)
    if (i < batch.n && bid >= batch.start[i]) g = i;
  TDesc D = batch.d[g];
  const int lt = bid - batch.start[g];
  const int trow = lt / D.tilesC;
  const int tcol = lt - trow * D.tilesC;
  const int r0 = trow * 64, c0 = tcol * 64;

  __shared__ float tile[64][65];
  const int t = threadIdx.x;
  const int sub = t >> 3, oct = t & 7;
  const float Wv = (D.mode == 2) ? *D.Wp : 0.f;

#pragma unroll
  for (int p = 0; p < 2; ++p) {
    const int rl = p * 32 + sub;
    const int cl0 = oct * 8;
    float vv[8];
    if (D.mode == 0) {
      const unsigned short* ip = (const unsigned short*)D.in1 + (size_t)(r0 + rl) * D.C + c0 + cl0;
      U16x8 tmp; tmp.v = *(const uint4*)ip;
#pragma unroll
      for (int i = 0; i < 8; ++i) vv[i] = bf2f(tmp.u[i]);
    } else {
      const float* ip = (const float*)D.in1 + (size_t)(r0 + rl) * D.C + c0 + cl0;
      f32x4 a = *(const f32x4*)ip, b = *(const f32x4*)(ip + 4);
#pragma unroll
      for (int i = 0; i < 4; ++i) { vv[i] = a[i]; vv[4+i] = b[i]; }
      if (D.mode == 2) {
        const float* ip2 = (const float*)D.in2 + (size_t)(r0 + rl) * D.C + c0 + cl0;
        f32x4 c = *(const f32x4*)ip2, d2 = *(const f32x4*)(ip2 + 4);
#pragma unroll
        for (int i = 0; i < 4; ++i) { vv[i] += Wv * c[i]; vv[4+i] += Wv * d2[i]; }
      }
    }
#pragma unroll
    for (int i = 0; i < 8; ++i) tile[cl0 + i][rl] = vv[i];
  }
  __syncthreads();
#pragma unroll
  for (int p = 0; p < 2; ++p) {
    const int cl = p * 32 + sub;
    const int rl0 = oct * 8;
    U16x8 h8, l8;
#pragma unroll
    for (int i = 0; i < 8; ++i) {
      float v = tile[cl][rl0 + i];
      unsigned short h = f2bf(v);
      h8.u[i] = h;
      l8.u[i] = f2bf(v - bf2f(h));
    }
    const size_t o = (size_t)(c0 + cl) * D.R + r0 + rl0;
    *(uint4*)(D.out_hi + o) = h8.v;
    if (D.mode != 0) *(uint4*)(D.out_lo + o) = l8.v;
  }
}

// ---------------------------------------------------------------------------
// batched MFMA GEMM, 128x128 tile, BK=32, 4 waves, split-bf16 via K-segments.
// A: [M][K] row-major k-contig (lda); B: [N][K] k-contig (ldb) -> C[M][N=1024].
// Epilogue via pointer flags:
//   heb_out != 0 : heb_out = clamp(heb_in + ALPHA*v)
//   else: out32a = v (if set); out32b = (accadd? out32b+v : v) (if set);
//         sp_hi/lo = split(relu(v + addin)) (if set)
// ---------------------------------------------------------------------------
struct GemmDesc {
  const unsigned short *A0, *A1, *A2;
  const unsigned short *B0, *B1, *B2;
  int nseg, segK, lda, ldb, accadd, pad0;
  float* out32a;
  float* out32b;
  const float* addin;
  unsigned short* sp_hi;
  unsigned short* sp_lo;
  const float* heb_in;
  float* heb_out;
};
struct GemmBatch { GemmDesc d[6]; int start[7]; int n; };

__global__ __launch_bounds__(256) void gemm_k(GemmBatch batch) {
  const int bid = blockIdx.x;
  int g = 0;
#pragma unroll
  for (int i = 1; i < 6; ++i)
    if (i < batch.n && bid >= batch.start[i]) g = i;
  GemmDesc D = batch.d[g];
  const int local = bid - batch.start[g];
  const int tm = local >> 3;       // tilesN fixed at 8 (N=1024)
  const int tn = local & 7;

  __shared__ __align__(16) unsigned short As[128 * 40];
  __shared__ __align__(16) unsigned short Bs[128 * 40];

  const int t = threadIdx.x;
  const int lane = t & 63;
  const int wave = t >> 6;
  const int wr = wave >> 1, wc = wave & 1;
  const int fr = lane & 15, fg = lane >> 4;

  const f32x4 vzero = {0.f, 0.f, 0.f, 0.f};
  f32x4 acc[4][4];
#pragma unroll
  for (int i = 0; i < 4; ++i)
#pragma unroll
    for (int j = 0; j < 4; ++j) acc[i][j] = vzero;

  const int srow = t >> 2;
  const int skc = (t & 3) * 8;
  const int kpseg = D.segK >> 5;
  const int ktot = D.nseg * kpseg;

  const size_t arow0 = (size_t)(tm * 128 + srow) * D.lda;
  const size_t arow1 = (size_t)(tm * 128 + srow + 64) * D.lda;
  const size_t brow0 = (size_t)(tn * 128 + srow) * D.ldb;
  const size_t brow1 = (size_t)(tn * 128 + srow + 64) * D.ldb;

  for (int kt = 0; kt < ktot; ++kt) {
    const int seg = (kt >= kpseg) + (kt >= 2 * kpseg);
    const int klocal = (kt - seg * kpseg) * 32 + skc;
    const unsigned short* Ap = (seg == 0) ? D.A0 : ((seg == 1) ? D.A1 : D.A2);
    const unsigned short* Bp = (seg == 0) ? D.B0 : ((seg == 1) ? D.B1 : D.B2);
    const uint4 av0 = *(const uint4*)(Ap + arow0 + klocal);
    const uint4 av1 = *(const uint4*)(Ap + arow1 + klocal);
    const uint4 bv0 = *(const uint4*)(Bp + brow0 + klocal);
    const uint4 bv1 = *(const uint4*)(Bp + brow1 + klocal);
    __syncthreads();
    *(uint4*)&As[srow * 40 + skc] = av0;
    *(uint4*)&As[(srow + 64) * 40 + skc] = av1;
    *(uint4*)&Bs[srow * 40 + skc] = bv0;
    *(uint4*)&Bs[(srow + 64) * 40 + skc] = bv1;
    __syncthreads();
    bf16x8 af[4], bf[4];
#pragma unroll
    for (int i = 0; i < 4; ++i)
      af[i] = *(const bf16x8*)&As[(wr * 64 + i * 16 + fr) * 40 + fg * 8];
#pragma unroll
    for (int j = 0; j < 4; ++j)
      bf[j] = *(const bf16x8*)&Bs[(wc * 64 + j * 16 + fr) * 40 + fg * 8];
#pragma unroll
    for (int i = 0; i < 4; ++i)
#pragma unroll
      for (int j = 0; j < 4; ++j)
        acc[i][j] = __builtin_amdgcn_mfma_f32_16x16x32_bf16(af[i], bf[j], acc[i][j], 0, 0, 0);
  }

  const int grb = tm * 128 + wr * 64 + fg * 4;
  const int gcb = tn * 128 + wc * 64 + fr;
#pragma unroll
  for (int i = 0; i < 4; ++i) {
#pragma unroll
    for (int j = 0; j < 4; ++j) {
      const int gc = gcb + j * 16;
#pragma unroll
      for (int r = 0; r < 4; ++r) {
        const int gr = grb + i * 16 + r;
        const size_t idx = (size_t)gr * NDIM + gc;
        const float v = acc[i][j][r];
        if (D.heb_out) {
          D.heb_out[idx] = fminf(fmaxf(D.heb_in[idx] + ALPHA * v, -CLAMPV), CLAMPV);
        } else {
          if (D.out32a) D.out32a[idx] = v;
          if (D.out32b) D.out32b[idx] = D.accadd ? (D.out32b[idx] + v) : v;
          if (D.sp_hi) {
            float rv = v + (D.addin ? D.addin[idx] : 0.f);
            rv = fmaxf(rv, 0.f);
            const unsigned short h = f2bf(rv);
            D.sp_hi[idx] = h;
            D.sp_lo[idx] = f2bf(rv - bf2f(h));
          }
        }
      }
    }
  }
}

// ---------------------------------------------------------------------------
// heb_h12y from 6 split-K partials
// ---------------------------------------------------------------------------
__global__ __launch_bounds__(256) void hebfix_k(const float* __restrict__ heb_in,
                                                const float* __restrict__ parts,
                                                float* __restrict__ out) {
  const size_t i0 = ((size_t)blockIdx.x * 256 + threadIdx.x) * 8;
#pragma unroll
  for (int u = 0; u < 2; ++u) {
    const size_t idx = i0 + u * 4;
    f32x4 s = *(const f32x4*)(parts + idx);
#pragma unroll
    for (int k = 1; k < 6; ++k) s += *(const f32x4*)(parts + (size_t)k * 1048576 + idx);
    f32x4 h = *(const f32x4*)(heb_in + idx);
    f32x4 o;
#pragma unroll
    for (int i = 0; i < 4; ++i) o[i] = fminf(fmaxf(h[i] + ALPHA * s[i], -CLAMPV), CLAMPV);
    *(f32x4*)(out + idx) = o;
  }
}

// ---------------------------------------------------------------------------
// y_out = ysum[:, :1022]
// ---------------------------------------------------------------------------
__global__ __launch_bounds__(256) void yassm_k(const float* __restrict__ ysum,
                                               float* __restrict__ yout) {
  const int stride = gridDim.x * 256;
  for (int idx = blockIdx.x * 256 + threadIdx.x; idx < BDIM * 1022; idx += stride) {
    const int row = idx / 1022;
    const int col = idx - row * 1022;
    yout[idx] = ysum[(size_t)row * NDIM + col];
  }
}

__global__ __launch_bounds__(256) void tanhcol_k(const float* __restrict__ ysum,
                                                 float* __restrict__ wpart,
                                                 float* __restrict__ dpart) {
  const int r = blockIdx.x * 256 + threadIdx.x;
  const size_t b = (size_t)r * NDIM;
  float tw = tanhf(ysum[b + 1022]);
  float td = tanhf(ysum[b + 1021]);
#pragma unroll
  for (int o = 32; o > 0; o >>= 1) { tw += __shfl_down(tw, o); td += __shfl_down(td, o); }
  __shared__ float s1[4], s2[4];
  const int lane = threadIdx.x & 63, wv = threadIdx.x >> 6;
  if (lane == 0) { s1[wv] = tw; s2[wv] = td; }
  __syncthreads();
  if (threadIdx.x == 0) {
    wpart[blockIdx.x] = s1[0] + s1[1] + s1[2] + s1[3];
    dpart[blockIdx.x] = s2[0] + s2[1] + s2[2] + s2[3];
  }
}

__global__ void finalize_k(const float* __restrict__ wpart, const float* __restrict__ dpart,
                           float* __restrict__ out, int nout) {
  if (threadIdx.x == 0 && blockIdx.x == 0) {
    float s = 0.f, d = 0.f;
    for (int i = 0; i < 16; ++i) { s += wpart[i]; d += dpart[i]; }
    out[nout - 2] = s * (1.f / BDIM);
    out[nout - 1] = d * (1.f / BDIM);
  }
}

// ---------------------------------------------------------------------------
extern "C" void kernel_launch(void* const* d_in, const int* in_sizes, int n_in,
                              void* d_out, int out_size, void* d_ws, size_t ws_size,
                              hipStream_t stream) {
  const float* x = (const float*)d_in[0];
  const float* wbase[6]; const float* hebin[6];
  for (int i = 0; i < 6; ++i) { wbase[i] = (const float*)d_in[1 + i]; hebin[i] = (const float*)d_in[7 + i]; }
  const float* Wp = (const float*)d_in[13];
  float* out = (float*)d_out;
  const size_t YOUT = (size_t)BDIM * 1022;
  float* hebout[6];
  for (int i = 0; i < 6; ++i) hebout[i] = out + YOUT + (size_t)i * 1048576;

  // ---- workspace layout: exactly 200 MiB, lifetime-aliased regions ----
  const size_t E = (size_t)BDIM * NDIM;          // 4194304 elements
  const size_t PAIRB = E * 4;                    // hi+lo bf16 pair bytes (16 MiB)
  const size_t WPAIRB = (size_t)NDIM * NDIM * 4; // weight hi+lo pair (4 MiB)
  const size_t FB = E * 4;                       // f32 buffer (16 MiB)
  const size_t REQUIRED = 7 * PAIRB + 6 * WPAIRB + 4 * FB;  // 209,715,200 B

  if (ws_size < REQUIRED) {
    // unambiguous "workspace too small" signal for the next round
    fill_k<<<(out_size + 255) / 256, 256, 0, stream>>>(out, out_size);
    return;
  }

  char* p = (char*)d_ws;
  auto takeB = [&](size_t n) -> char* { char* q = p; p += n; return q; };

  // R0: x pair -> h1 pair       R1: xT pair -> h1T pair
  // R2: h0 pair -> fT5 pair     R3: h0T pair
  // R4: fT0 -> fT2 -> part[0:4M)   R5: fT1 -> fT4 -> part[4M:6M)
  // R6: fT3 -> wpart/dpart
  unsigned short* R0 = (unsigned short*)takeB(PAIRB);
  unsigned short* R1 = (unsigned short*)takeB(PAIRB);
  unsigned short* R2 = (unsigned short*)takeB(PAIRB);
  unsigned short* R3 = (unsigned short*)takeB(PAIRB);
  unsigned short* R4 = (unsigned short*)takeB(PAIRB);
  unsigned short* R5 = (unsigned short*)takeB(PAIRB);
  unsigned short* R6 = (unsigned short*)takeB(PAIRB);
  unsigned short* WThi[6]; unsigned short* WTlo[6];
  for (int i = 0; i < 6; ++i) {
    WThi[i] = (unsigned short*)takeB(WPAIRB);
    WTlo[i] = WThi[i] + (size_t)NDIM * NDIM;
  }
  float* F0 = (float*)takeB(FB);   // h0x -> h10
  float* F1 = (float*)takeB(FB);   // h1x -> y1tmp
  float* F2 = (float*)takeB(FB);   // yxtmp -> y0tmp
  float* F3 = (float*)takeB(FB);   // ysum (live to end)

  unsigned short *xhi = R0, *xlo = R0 + E;          // also h1hi/h1lo later
  unsigned short *xThi = R1, *xTlo = R1 + E;        // also h1Thi/h1Tlo later
  unsigned short *h0hi = R2, *h0lo = R2 + E;        // also fT5 later
  unsigned short *h0Thi = R3, *h0Tlo = R3 + E;
  float* part = (float*)R4;                         // 6M floats spans R4+R5
  float* wpart = (float*)R6; float* dpart = wpart + 64;

  // ---- s1: split x ----
  split_x_k<<<2048, 256, 0, stream>>>(x, xhi, xlo);

  // ---- s2: Weff^T splits (6) + x^T split ----
  {
    TBatch tb{};
    int s = 0;
    for (int i = 0; i < 6; ++i) {
      tb.d[i] = { wbase[i], hebin[i], Wp, WThi[i], WTlo[i], NDIM, NDIM, NDIM / 64, 2 };
      tb.start[i] = s; s += (NDIM / 64) * (NDIM / 64);
    }
    tb.d[6] = { x, nullptr, nullptr, xThi, xTlo, BDIM, NDIM, NDIM / 64, 1 };
    tb.start[6] = s; s += (BDIM / 64) * (NDIM / 64);
    tb.start[7] = s; tb.n = 7;
    transpose_k<<<s, 256, 0, stream>>>(tb);
  }

  auto fwdDesc = [&](const unsigned short* ahi, const unsigned short* alo, int wi) -> GemmDesc {
    GemmDesc d{};
    d.A0 = ahi; d.A1 = ahi; d.A2 = alo;
    d.B0 = WThi[wi]; d.B1 = WTlo[wi]; d.B2 = WThi[wi];
    d.nseg = 3; d.segK = NDIM; d.lda = NDIM; d.ldb = NDIM;
    return d;
  };
  auto hebDesc = [&](const unsigned short* ahi, const unsigned short* alo,
                     const unsigned short* bhi, const unsigned short* blo,
                     int hi) -> GemmDesc {
    GemmDesc d{};
    d.A0 = ahi; d.A1 = ahi; d.A2 = alo;
    d.B0 = bhi; d.B1 = blo; d.B2 = bhi;
    d.nseg = 3; d.segK = BDIM; d.lda = BDIM; d.ldb = BDIM;
    d.heb_in = hebin[hi]; d.heb_out = hebout[hi];
    return d;
  };

  // ---- s3: h0x, h1x, yx ----
  {
    GemmBatch gb{};
    gb.d[0] = fwdDesc(xhi, xlo, 0);                       // h0x
    gb.d[0].out32a = F0; gb.d[0].sp_hi = h0hi; gb.d[0].sp_lo = h0lo;
    gb.d[1] = fwdDesc(xhi, xlo, 1);                       // h1x
    gb.d[1].out32a = F1;
    gb.d[2] = fwdDesc(xhi, xlo, 3);                       // yx
    gb.d[2].out32a = F2; gb.d[2].out32b = F3; gb.d[2].accadd = 0;
    gb.start[0] = 0; gb.start[1] = 256; gb.start[2] = 512; gb.start[3] = 768;
    gb.n = 3;
    gemm_k<<<768, 256, 0, stream>>>(gb);
  }

  // ---- s4: fT0=h0x^T, fT1=h1x^T, fT3=yx^T (splits); h0T hi/lo ----
  {
    TBatch tb{};
    tb.d[0] = { F0, nullptr, nullptr, R4, R4 + E, BDIM, NDIM, NDIM / 64, 1 };
    tb.d[1] = { F1, nullptr, nullptr, R5, R5 + E, BDIM, NDIM, NDIM / 64, 1 };
    tb.d[2] = { F2, nullptr, nullptr, R6, R6 + E, BDIM, NDIM, NDIM / 64, 1 };
    tb.d[3] = { h0hi, nullptr, nullptr, h0Thi, nullptr, BDIM, NDIM, NDIM / 64, 0 };
    tb.d[4] = { h0lo, nullptr, nullptr, h0Tlo, nullptr, BDIM, NDIM, NDIM / 64, 0 };
    for (int i = 0; i < 6; ++i) tb.start[i] = i * 1024;
    tb.n = 5;
    transpose_k<<<5120, 256, 0, stream>>>(tb);
  }

  // ---- s5: h10 (+relu split into R0), y0 (ysum+=), heb{x2h0,x2h1,x2y} ----
  {
    GemmBatch gb{};
    gb.d[0] = fwdDesc(h0hi, h0lo, 2);                     // h1_0
    gb.d[0].out32a = F0; gb.d[0].addin = F1; gb.d[0].sp_hi = R0; gb.d[0].sp_lo = R0 + E;
    gb.d[1] = fwdDesc(h0hi, h0lo, 4);                     // y0
    gb.d[1].out32a = F2; gb.d[1].out32b = F3; gb.d[1].accadd = 1;
    gb.d[2] = hebDesc(xThi, xTlo, R4, R4 + E, 0);         // heb_x2h0
    gb.d[3] = hebDesc(xThi, xTlo, R5, R5 + E, 1);         // heb_x2h1
    gb.d[4] = hebDesc(xThi, xTlo, R6, R6 + E, 3);         // heb_x2y
    gb.start[0] = 0; gb.start[1] = 256; gb.start[2] = 512;
    gb.start[3] = 576; gb.start[4] = 640; gb.start[5] = 704;
    gb.n = 5;
    gemm_k<<<704, 256, 0, stream>>>(gb);
  }

  // ---- s6: fT2=h10^T, fT4=y0^T (splits); h1T hi/lo into R1 ----
  {
    TBatch tb{};
    tb.d[0] = { F0, nullptr, nullptr, R4, R4 + E, BDIM, NDIM, NDIM / 64, 1 };
    tb.d[1] = { F2, nullptr, nullptr, R5, R5 + E, BDIM, NDIM, NDIM / 64, 1 };
    tb.d[2] = { R0, nullptr, nullptr, R1, nullptr, BDIM, NDIM, NDIM / 64, 0 };      // h1hi -> h1Thi
    tb.d[3] = { R0 + E, nullptr, nullptr, R1 + E, nullptr, BDIM, NDIM, NDIM / 64, 0 }; // h1lo -> h1Tlo
    for (int i = 0; i < 5; ++i) tb.start[i] = i * 1024;
    tb.n = 4;
    transpose_k<<<4096, 256, 0, stream>>>(tb);
  }

  // ---- s7: y1 (ysum+=), heb{h02h1, h02y} ----
  {
    GemmBatch gb{};
    gb.d[0] = fwdDesc(R0, R0 + E, 5);                     // y1 (A = h1 pair)
    gb.d[0].out32a = F1; gb.d[0].out32b = F3; gb.d[0].accadd = 1;
    gb.d[1] = hebDesc(h0Thi, h0Tlo, R4, R4 + E, 2);       // heb_h02h1
    gb.d[2] = hebDesc(h0Thi, h0Tlo, R5, R5 + E, 4);       // heb_h02y
    gb.start[0] = 0; gb.start[1] = 256; gb.start[2] = 320; gb.start[3] = 384;
    gb.n = 3;
    gemm_k<<<384, 256, 0, stream>>>(gb);
  }

  // ---- s8: fT5 = y1^T split into R2 ----
  {
    TBatch tb{};
    tb.d[0] = { F1, nullptr, nullptr, R2, R2 + E, BDIM, NDIM, NDIM / 64, 1 };
    tb.start[0] = 0; tb.start[1] = 1024; tb.n = 1;
    transpose_k<<<1024, 256, 0, stream>>>(tb);
  }

  // ---- s9: heb_h12y split-K into 6 partials (A = h1T in R1, B = fT5 in R2) ----
  {
    const unsigned short* ap[3] = { R1, R1, R1 + E };
    const unsigned short* bp[3] = { R2, R2 + E, R2 };
    GemmBatch gb{};
    for (int pp = 0; pp < 3; ++pp)
      for (int h = 0; h < 2; ++h) {
        GemmDesc d{};
        d.A0 = ap[pp] + h * 2048; d.A1 = d.A0; d.A2 = d.A0;
        d.B0 = bp[pp] + h * 2048; d.B1 = d.B0; d.B2 = d.B0;
        d.nseg = 1; d.segK = 2048; d.lda = BDIM; d.ldb = BDIM;
        d.out32a = part + (size_t)(pp * 2 + h) * 1048576;
        gb.d[pp * 2 + h] = d;
      }
    for (int i = 0; i <= 6; ++i) gb.start[i] = i * 64;
    gb.n = 6;
    gemm_k<<<384, 256, 0, stream>>>(gb);
  }

  // ---- s10-s13: heb fix, y assembly, tanh means ----
  hebfix_k<<<512, 256, 0, stream>>>(hebin[5], part, hebout[5]);
  yassm_k<<<2048, 256, 0, stream>>>(F3, out);
  tanhcol_k<<<16, 256, 0, stream>>>(F3, wpart, dpart);
  finalize_k<<<1, 64, 0, stream>>>(wpart, dpart, out, out_size);
}

// Round 3
// 732.453 us; speedup vs baseline: 1.3285x; 1.3285x over previous
//
#include <hip/hip_runtime.h>
#include <stdint.h>

#define ALPHA 0.3f
#define CLAMPV 0.3f
#define BDIM 4096
#define NDIM 1024

typedef float f32x4 __attribute__((ext_vector_type(4)));
typedef __bf16 bf16x8 __attribute__((ext_vector_type(8)));

union U16x8 { uint4 v; unsigned short u[8]; };

__device__ __forceinline__ float bf2f(unsigned short u) {
  union { unsigned int i; float f; } c; c.i = ((unsigned int)u) << 16; return c.f;
}
__device__ __forceinline__ unsigned short f2bf(float f) {
  union { float f; unsigned int i; } c; c.f = f;
  unsigned int u = c.i;
  unsigned int r = u + 0x7FFFu + ((u >> 16) & 1u);
  return (unsigned short)(r >> 16);
}

// ---------------------------------------------------------------------------
// ws-too-small signal: fill output with a recognizable constant
// ---------------------------------------------------------------------------
__global__ __launch_bounds__(256) void fill_k(float* __restrict__ out, int n) {
  int i = blockIdx.x * 256 + threadIdx.x;
  if (i < n) out[i] = 12345.0f;
}

// ---------------------------------------------------------------------------
// split x (f32) -> bf16 hi/lo
// ---------------------------------------------------------------------------
__global__ __launch_bounds__(256) void split_x_k(const float* __restrict__ x,
                                                 unsigned short* __restrict__ hi,
                                                 unsigned short* __restrict__ lo) {
  const size_t i0 = ((size_t)blockIdx.x * 256 + threadIdx.x) * 8;
  f32x4 a = *(const f32x4*)(x + i0);
  f32x4 b = *(const f32x4*)(x + i0 + 4);
  U16x8 h8, l8;
#pragma unroll
  for (int i = 0; i < 4; ++i) {
    unsigned short h = f2bf(a[i]); h8.u[i] = h; l8.u[i] = f2bf(a[i] - bf2f(h));
    unsigned short h2 = f2bf(b[i]); h8.u[4+i] = h2; l8.u[4+i] = f2bf(b[i] - bf2f(h2));
  }
  *(uint4*)(hi + i0) = h8.v;
  *(uint4*)(lo + i0) = l8.v;
}

// ---------------------------------------------------------------------------
// batched tiled transpose: out[C][R] (bf16 hi / optional lo) from in[R][C]
// mode 0: bf16 in -> bf16 out (hi only, lossless)
// mode 1: f32 in  -> split hi/lo
// mode 2: (in1 + W*in2) f32 -> split hi/lo   (Weff prep)
// ---------------------------------------------------------------------------
struct TDesc {
  const void* in1; const void* in2; const float* Wp;
  unsigned short* out_hi; unsigned short* out_lo;
  int R, C, tilesC, mode;
};
struct TBatch { TDesc d[8]; int start[9]; int n; };

__global__ __launch_bounds__(256) void transpose_k(TBatch batch) {
  const int bid = blockIdx.x;
  int g = 0;
#pragma unroll
  for (int i = 1; i < 8; ++i)
    if (i < batch.n && bid >= batch.start[i]) g = i;
  TDesc D = batch.d[g];
  const int lt = bid - batch.start[g];
  const int trow = lt / D.tilesC;
  const int tcol = lt - trow * D.tilesC;
  const int r0 = trow * 64, c0 = tcol * 64;

  __shared__ float tile[64][65];
  const int t = threadIdx.x;
  const int sub = t >> 3, oct = t & 7;
  const float Wv = (D.mode == 2) ? *D.Wp : 0.f;

#pragma unroll
  for (int p = 0; p < 2; ++p) {
    const int rl = p * 32 + sub;
    const int cl0 = oct * 8;
    float vv[8];
    if (D.mode == 0) {
      const unsigned short* ip = (const unsigned short*)D.in1 + (size_t)(r0 + rl) * D.C + c0 + cl0;
      U16x8 tmp; tmp.v = *(const uint4*)ip;
#pragma unroll
      for (int i = 0; i < 8; ++i) vv[i] = bf2f(tmp.u[i]);
    } else {
      const float* ip = (const float*)D.in1 + (size_t)(r0 + rl) * D.C + c0 + cl0;
      f32x4 a = *(const f32x4*)ip, b = *(const f32x4*)(ip + 4);
#pragma unroll
      for (int i = 0; i < 4; ++i) { vv[i] = a[i]; vv[4+i] = b[i]; }
      if (D.mode == 2) {
        const float* ip2 = (const float*)D.in2 + (size_t)(r0 + rl) * D.C + c0 + cl0;
        f32x4 c = *(const f32x4*)ip2, d2 = *(const f32x4*)(ip2 + 4);
#pragma unroll
        for (int i = 0; i < 4; ++i) { vv[i] += Wv * c[i]; vv[4+i] += Wv * d2[i]; }
      }
    }
#pragma unroll
    for (int i = 0; i < 8; ++i) tile[cl0 + i][rl] = vv[i];
  }
  __syncthreads();
#pragma unroll
  for (int p = 0; p < 2; ++p) {
    const int cl = p * 32 + sub;
    const int rl0 = oct * 8;
    U16x8 h8, l8;
#pragma unroll
    for (int i = 0; i < 8; ++i) {
      float v = tile[cl][rl0 + i];
      unsigned short h = f2bf(v);
      h8.u[i] = h;
      l8.u[i] = f2bf(v - bf2f(h));
    }
    const size_t o = (size_t)(c0 + cl) * D.R + r0 + rl0;
    *(uint4*)(D.out_hi + o) = h8.v;
    if (D.mode != 0) *(uint4*)(D.out_lo + o) = l8.v;
  }
}

// ---------------------------------------------------------------------------
// batched MFMA GEMM, 128x128 tile, BK=32, 4 waves, split-bf16 via K-segments.
// A: [M][K] row-major k-contig (lda); B: [N][K] k-contig (ldb) -> C[M][N=1024].
// Staging: global_load_lds width=16, linear LDS [128][32] (8KB each).
// XOR swizzle (both sides): logical k-slot ^= (row>>1)&3 — applied to the
// per-lane GLOBAL source address AND to the ds_read fragment offsets
// (rule #21: linear dest + inverse-swz source + swz on read).
// Epilogue via pointer flags (unchanged from round 2).
// ---------------------------------------------------------------------------
struct GemmDesc {
  const unsigned short *A0, *A1, *A2;
  const unsigned short *B0, *B1, *B2;
  int nseg, segK, lda, ldb, accadd, pad0;
  float* out32a;
  float* out32b;
  const float* addin;
  unsigned short* sp_hi;
  unsigned short* sp_lo;
  const float* heb_in;
  float* heb_out;
};
struct GemmBatch { GemmDesc d[6]; int start[7]; int n; };

__global__ __launch_bounds__(256) void gemm_k(GemmBatch batch) {
  const int bid = blockIdx.x;
  int g = 0;
#pragma unroll
  for (int i = 1; i < 6; ++i)
    if (i < batch.n && bid >= batch.start[i]) g = i;
  GemmDesc D = batch.d[g];
  const int local = bid - batch.start[g];
  const int tm = local >> 3;       // tilesN fixed at 8 (N=1024)
  const int tn = local & 7;

  __shared__ __align__(16) unsigned short As[128 * 32];   // 8 KB, linear
  __shared__ __align__(16) unsigned short Bs[128 * 32];   // 8 KB, linear

  const int t = threadIdx.x;
  const int lane = t & 63;
  const int wave = t >> 6;
  const int wr = wave >> 1, wc = wave & 1;
  const int fr = lane & 15, fg = lane >> 4;

  const f32x4 vzero = {0.f, 0.f, 0.f, 0.f};
  f32x4 acc[4][4];
#pragma unroll
  for (int i = 0; i < 4; ++i)
#pragma unroll
    for (int j = 0; j < 4; ++j) acc[i][j] = vzero;

  // ---- staging geometry: thread t owns LDS bytes [t*16, t*16+16) ----
  // LDS byte L holds logical (row = L/64, kbyte = (L%64) ^ ((row>>1&3)<<4))
  const int sr = t >> 2;                               // row 0..63 (lower half)
  const int ks = ((t & 3) ^ ((sr >> 1) & 3)) * 8;      // swizzled k-elem offset
  unsigned short* AsW = As + wave * 512;               // wave-uniform LDS dst
  unsigned short* BsW = Bs + wave * 512;

  // ---- fragment ds_read byte offsets (K-invariant, swizzled) ----
  int aoff[4], boff[4];
#pragma unroll
  for (int i = 0; i < 4; ++i) {
    const int ra = wr * 64 + i * 16 + fr;
    aoff[i] = ra * 64 + ((fg ^ ((ra >> 1) & 3)) << 4);
    const int rb = wc * 64 + i * 16 + fr;
    boff[i] = rb * 64 + ((fg ^ ((rb >> 1) & 3)) << 4);
  }
  const char* Asb = (const char*)As;
  const char* Bsb = (const char*)Bs;

  const size_t arow0 = (size_t)(tm * 128 + sr) * D.lda + ks;
  const size_t arow1 = (size_t)(tm * 128 + sr + 64) * D.lda + ks;
  const size_t brow0 = (size_t)(tn * 128 + sr) * D.ldb + ks;
  const size_t brow1 = (size_t)(tn * 128 + sr + 64) * D.ldb + ks;
  const int kpseg = D.segK >> 5;

  for (int seg = 0; seg < D.nseg; ++seg) {
    const unsigned short* Ap = (seg == 0) ? D.A0 : ((seg == 1) ? D.A1 : D.A2);
    const unsigned short* Bp = (seg == 0) ? D.B0 : ((seg == 1) ? D.B1 : D.B2);
    for (int kk = 0; kk < kpseg; ++kk) {
      const int kb = kk << 5;
      __builtin_amdgcn_global_load_lds(
          (const __attribute__((address_space(1))) void*)(Ap + arow0 + kb),
          (__attribute__((address_space(3))) void*)AsW, 16, 0, 0);
      __builtin_amdgcn_global_load_lds(
          (const __attribute__((address_space(1))) void*)(Ap + arow1 + kb),
          (__attribute__((address_space(3))) void*)(AsW + 2048), 16, 0, 0);
      __builtin_amdgcn_global_load_lds(
          (const __attribute__((address_space(1))) void*)(Bp + brow0 + kb),
          (__attribute__((address_space(3))) void*)BsW, 16, 0, 0);
      __builtin_amdgcn_global_load_lds(
          (const __attribute__((address_space(1))) void*)(Bp + brow1 + kb),
          (__attribute__((address_space(3))) void*)(BsW + 2048), 16, 0, 0);
      __syncthreads();   // compiler drains vmcnt(0) before s_barrier
      bf16x8 af[4], bfr[4];
#pragma unroll
      for (int i = 0; i < 4; ++i) af[i] = *(const bf16x8*)(Asb + aoff[i]);
#pragma unroll
      for (int j = 0; j < 4; ++j) bfr[j] = *(const bf16x8*)(Bsb + boff[j]);
#pragma unroll
      for (int i = 0; i < 4; ++i)
#pragma unroll
        for (int j = 0; j < 4; ++j)
          acc[i][j] = __builtin_amdgcn_mfma_f32_16x16x32_bf16(af[i], bfr[j], acc[i][j], 0, 0, 0);
      __syncthreads();   // all waves done reading before next stage
    }
  }

  const int grb = tm * 128 + wr * 64 + fg * 4;
  const int gcb = tn * 128 + wc * 64 + fr;
#pragma unroll
  for (int i = 0; i < 4; ++i) {
#pragma unroll
    for (int j = 0; j < 4; ++j) {
      const int gc = gcb + j * 16;
#pragma unroll
      for (int r = 0; r < 4; ++r) {
        const int gr = grb + i * 16 + r;
        const size_t idx = (size_t)gr * NDIM + gc;
        const float v = acc[i][j][r];
        if (D.heb_out) {
          D.heb_out[idx] = fminf(fmaxf(D.heb_in[idx] + ALPHA * v, -CLAMPV), CLAMPV);
        } else {
          if (D.out32a) D.out32a[idx] = v;
          if (D.out32b) D.out32b[idx] = D.accadd ? (D.out32b[idx] + v) : v;
          if (D.sp_hi) {
            float rv = v + (D.addin ? D.addin[idx] : 0.f);
            rv = fmaxf(rv, 0.f);
            const unsigned short h = f2bf(rv);
            D.sp_hi[idx] = h;
            D.sp_lo[idx] = f2bf(rv - bf2f(h));
          }
        }
      }
    }
  }
}

// ---------------------------------------------------------------------------
// heb_h12y from 6 split-K partials
// ---------------------------------------------------------------------------
__global__ __launch_bounds__(256) void hebfix_k(const float* __restrict__ heb_in,
                                                const float* __restrict__ parts,
                                                float* __restrict__ out) {
  const size_t i0 = ((size_t)blockIdx.x * 256 + threadIdx.x) * 8;
#pragma unroll
  for (int u = 0; u < 2; ++u) {
    const size_t idx = i0 + u * 4;
    f32x4 s = *(const f32x4*)(parts + idx);
#pragma unroll
    for (int k = 1; k < 6; ++k) s += *(const f32x4*)(parts + (size_t)k * 1048576 + idx);
    f32x4 h = *(const f32x4*)(heb_in + idx);
    f32x4 o;
#pragma unroll
    for (int i = 0; i < 4; ++i) o[i] = fminf(fmaxf(h[i] + ALPHA * s[i], -CLAMPV), CLAMPV);
    *(f32x4*)(out + idx) = o;
  }
}

// ---------------------------------------------------------------------------
// y_out = ysum[:, :1022]
// ---------------------------------------------------------------------------
__global__ __launch_bounds__(256) void yassm_k(const float* __restrict__ ysum,
                                               float* __restrict__ yout) {
  const int stride = gridDim.x * 256;
  for (int idx = blockIdx.x * 256 + threadIdx.x; idx < BDIM * 1022; idx += stride) {
    const int row = idx / 1022;
    const int col = idx - row * 1022;
    yout[idx] = ysum[(size_t)row * NDIM + col];
  }
}

__global__ __launch_bounds__(256) void tanhcol_k(const float* __restrict__ ysum,
                                                 float* __restrict__ wpart,
                                                 float* __restrict__ dpart) {
  const int r = blockIdx.x * 256 + threadIdx.x;
  const size_t b = (size_t)r * NDIM;
  float tw = tanhf(ysum[b + 1022]);
  float td = tanhf(ysum[b + 1021]);
#pragma unroll
  for (int o = 32; o > 0; o >>= 1) { tw += __shfl_down(tw, o); td += __shfl_down(td, o); }
  __shared__ float s1[4], s2[4];
  const int lane = threadIdx.x & 63, wv = threadIdx.x >> 6;
  if (lane == 0) { s1[wv] = tw; s2[wv] = td; }
  __syncthreads();
  if (threadIdx.x == 0) {
    wpart[blockIdx.x] = s1[0] + s1[1] + s1[2] + s1[3];
    dpart[blockIdx.x] = s2[0] + s2[1] + s2[2] + s2[3];
  }
}

__global__ void finalize_k(const float* __restrict__ wpart, const float* __restrict__ dpart,
                           float* __restrict__ out, int nout) {
  if (threadIdx.x == 0 && blockIdx.x == 0) {
    float s = 0.f, d = 0.f;
    for (int i = 0; i < 16; ++i) { s += wpart[i]; d += dpart[i]; }
    out[nout - 2] = s * (1.f / BDIM);
    out[nout - 1] = d * (1.f / BDIM);
  }
}

// ---------------------------------------------------------------------------
extern "C" void kernel_launch(void* const* d_in, const int* in_sizes, int n_in,
                              void* d_out, int out_size, void* d_ws, size_t ws_size,
                              hipStream_t stream) {
  const float* x = (const float*)d_in[0];
  const float* wbase[6]; const float* hebin[6];
  for (int i = 0; i < 6; ++i) { wbase[i] = (const float*)d_in[1 + i]; hebin[i] = (const float*)d_in[7 + i]; }
  const float* Wp = (const float*)d_in[13];
  float* out = (float*)d_out;
  const size_t YOUT = (size_t)BDIM * 1022;
  float* hebout[6];
  for (int i = 0; i < 6; ++i) hebout[i] = out + YOUT + (size_t)i * 1048576;

  // ---- workspace layout: exactly 200 MiB, lifetime-aliased regions ----
  const size_t E = (size_t)BDIM * NDIM;          // 4194304 elements
  const size_t PAIRB = E * 4;                    // hi+lo bf16 pair bytes (16 MiB)
  const size_t WPAIRB = (size_t)NDIM * NDIM * 4; // weight hi+lo pair (4 MiB)
  const size_t FB = E * 4;                       // f32 buffer (16 MiB)
  const size_t REQUIRED = 7 * PAIRB + 6 * WPAIRB + 4 * FB;  // 209,715,200 B

  if (ws_size < REQUIRED) {
    fill_k<<<(out_size + 255) / 256, 256, 0, stream>>>(out, out_size);
    return;
  }

  char* p = (char*)d_ws;
  auto takeB = [&](size_t n) -> char* { char* q = p; p += n; return q; };

  // R0: x pair -> h1 pair       R1: xT pair -> h1T pair
  // R2: h0 pair -> fT5 pair     R3: h0T pair
  // R4: fT0 -> fT2 -> part[0:4M)   R5: fT1 -> fT4 -> part[4M:6M)
  // R6: fT3 -> wpart/dpart
  unsigned short* R0 = (unsigned short*)takeB(PAIRB);
  unsigned short* R1 = (unsigned short*)takeB(PAIRB);
  unsigned short* R2 = (unsigned short*)takeB(PAIRB);
  unsigned short* R3 = (unsigned short*)takeB(PAIRB);
  unsigned short* R4 = (unsigned short*)takeB(PAIRB);
  unsigned short* R5 = (unsigned short*)takeB(PAIRB);
  unsigned short* R6 = (unsigned short*)takeB(PAIRB);
  unsigned short* WThi[6]; unsigned short* WTlo[6];
  for (int i = 0; i < 6; ++i) {
    WThi[i] = (unsigned short*)takeB(WPAIRB);
    WTlo[i] = WThi[i] + (size_t)NDIM * NDIM;
  }
  float* F0 = (float*)takeB(FB);   // h0x -> h10
  float* F1 = (float*)takeB(FB);   // h1x -> y1tmp
  float* F2 = (float*)takeB(FB);   // yxtmp -> y0tmp
  float* F3 = (float*)takeB(FB);   // ysum (live to end)

  unsigned short *xhi = R0, *xlo = R0 + E;          // also h1hi/h1lo later
  unsigned short *xThi = R1, *xTlo = R1 + E;        // also h1Thi/h1Tlo later
  unsigned short *h0hi = R2, *h0lo = R2 + E;        // also fT5 later
  unsigned short *h0Thi = R3, *h0Tlo = R3 + E;
  float* part = (float*)R4;                         // 6M floats spans R4+R5
  float* wpart = (float*)R6; float* dpart = wpart + 64;

  // ---- s1: split x ----
  split_x_k<<<2048, 256, 0, stream>>>(x, xhi, xlo);

  // ---- s2: Weff^T splits (6) + x^T split ----
  {
    TBatch tb{};
    int s = 0;
    for (int i = 0; i < 6; ++i) {
      tb.d[i] = { wbase[i], hebin[i], Wp, WThi[i], WTlo[i], NDIM, NDIM, NDIM / 64, 2 };
      tb.start[i] = s; s += (NDIM / 64) * (NDIM / 64);
    }
    tb.d[6] = { x, nullptr, nullptr, xThi, xTlo, BDIM, NDIM, NDIM / 64, 1 };
    tb.start[6] = s; s += (BDIM / 64) * (NDIM / 64);
    tb.start[7] = s; tb.n = 7;
    transpose_k<<<s, 256, 0, stream>>>(tb);
  }

  auto fwdDesc = [&](const unsigned short* ahi, const unsigned short* alo, int wi) -> GemmDesc {
    GemmDesc d{};
    d.A0 = ahi; d.A1 = ahi; d.A2 = alo;
    d.B0 = WThi[wi]; d.B1 = WTlo[wi]; d.B2 = WThi[wi];
    d.nseg = 3; d.segK = NDIM; d.lda = NDIM; d.ldb = NDIM;
    return d;
  };
  auto hebDesc = [&](const unsigned short* ahi, const unsigned short* alo,
                     const unsigned short* bhi, const unsigned short* blo,
                     int hi) -> GemmDesc {
    GemmDesc d{};
    d.A0 = ahi; d.A1 = ahi; d.A2 = alo;
    d.B0 = bhi; d.B1 = blo; d.B2 = bhi;
    d.nseg = 3; d.segK = BDIM; d.lda = BDIM; d.ldb = BDIM;
    d.heb_in = hebin[hi]; d.heb_out = hebout[hi];
    return d;
  };

  // ---- s3: h0x, h1x, yx ----
  {
    GemmBatch gb{};
    gb.d[0] = fwdDesc(xhi, xlo, 0);                       // h0x
    gb.d[0].out32a = F0; gb.d[0].sp_hi = h0hi; gb.d[0].sp_lo = h0lo;
    gb.d[1] = fwdDesc(xhi, xlo, 1);                       // h1x
    gb.d[1].out32a = F1;
    gb.d[2] = fwdDesc(xhi, xlo, 3);                       // yx
    gb.d[2].out32a = F2; gb.d[2].out32b = F3; gb.d[2].accadd = 0;
    gb.start[0] = 0; gb.start[1] = 256; gb.start[2] = 512; gb.start[3] = 768;
    gb.n = 3;
    gemm_k<<<768, 256, 0, stream>>>(gb);
  }

  // ---- s4: fT0=h0x^T, fT1=h1x^T, fT3=yx^T (splits); h0T hi/lo ----
  {
    TBatch tb{};
    tb.d[0] = { F0, nullptr, nullptr, R4, R4 + E, BDIM, NDIM, NDIM / 64, 1 };
    tb.d[1] = { F1, nullptr, nullptr, R5, R5 + E, BDIM, NDIM, NDIM / 64, 1 };
    tb.d[2] = { F2, nullptr, nullptr, R6, R6 + E, BDIM, NDIM, NDIM / 64, 1 };
    tb.d[3] = { h0hi, nullptr, nullptr, h0Thi, nullptr, BDIM, NDIM, NDIM / 64, 0 };
    tb.d[4] = { h0lo, nullptr, nullptr, h0Tlo, nullptr, BDIM, NDIM, NDIM / 64, 0 };
    for (int i = 0; i < 6; ++i) tb.start[i] = i * 1024;
    tb.n = 5;
    transpose_k<<<5120, 256, 0, stream>>>(tb);
  }

  // ---- s5: h10 (+relu split into R0), y0 (ysum+=), heb{x2h0,x2h1,x2y} ----
  {
    GemmBatch gb{};
    gb.d[0] = fwdDesc(h0hi, h0lo, 2);                     // h1_0
    gb.d[0].out32a = F0; gb.d[0].addin = F1; gb.d[0].sp_hi = R0; gb.d[0].sp_lo = R0 + E;
    gb.d[1] = fwdDesc(h0hi, h0lo, 4);                     // y0
    gb.d[1].out32a = F2; gb.d[1].out32b = F3; gb.d[1].accadd = 1;
    gb.d[2] = hebDesc(xThi, xTlo, R4, R4 + E, 0);         // heb_x2h0
    gb.d[3] = hebDesc(xThi, xTlo, R5, R5 + E, 1);         // heb_x2h1
    gb.d[4] = hebDesc(xThi, xTlo, R6, R6 + E, 3);         // heb_x2y
    gb.start[0] = 0; gb.start[1] = 256; gb.start[2] = 512;
    gb.start[3] = 576; gb.start[4] = 640; gb.start[5] = 704;
    gb.n = 5;
    gemm_k<<<704, 256, 0, stream>>>(gb);
  }

  // ---- s6: fT2=h10^T, fT4=y0^T (splits); h1T hi/lo into R1 ----
  {
    TBatch tb{};
    tb.d[0] = { F0, nullptr, nullptr, R4, R4 + E, BDIM, NDIM, NDIM / 64, 1 };
    tb.d[1] = { F2, nullptr, nullptr, R5, R5 + E, BDIM, NDIM, NDIM / 64, 1 };
    tb.d[2] = { R0, nullptr, nullptr, R1, nullptr, BDIM, NDIM, NDIM / 64, 0 };      // h1hi -> h1Thi
    tb.d[3] = { R0 + E, nullptr, nullptr, R1 + E, nullptr, BDIM, NDIM, NDIM / 64, 0 }; // h1lo -> h1Tlo
    for (int i = 0; i < 5; ++i) tb.start[i] = i * 1024;
    tb.n = 4;
    transpose_k<<<4096, 256, 0, stream>>>(tb);
  }

  // ---- s7: y1 (ysum+=), heb{h02h1, h02y} ----
  {
    GemmBatch gb{};
    gb.d[0] = fwdDesc(R0, R0 + E, 5);                     // y1 (A = h1 pair)
    gb.d[0].out32a = F1; gb.d[0].out32b = F3; gb.d[0].accadd = 1;
    gb.d[1] = hebDesc(h0Thi, h0Tlo, R4, R4 + E, 2);       // heb_h02h1
    gb.d[2] = hebDesc(h0Thi, h0Tlo, R5, R5 + E, 4);       // heb_h02y
    gb.start[0] = 0; gb.start[1] = 256; gb.start[2] = 320; gb.start[3] = 384;
    gb.n = 3;
    gemm_k<<<384, 256, 0, stream>>>(gb);
  }

  // ---- s8: fT5 = y1^T split into R2 ----
  {
    TBatch tb{};
    tb.d[0] = { F1, nullptr, nullptr, R2, R2 + E, BDIM, NDIM, NDIM / 64, 1 };
    tb.start[0] = 0; tb.start[1] = 1024; tb.n = 1;
    transpose_k<<<1024, 256, 0, stream>>>(tb);
  }

  // ---- s9: heb_h12y split-K into 6 partials (A = h1T in R1, B = fT5 in R2) ----
  {
    const unsigned short* ap[3] = { R1, R1, R1 + E };
    const unsigned short* bp[3] = { R2, R2 + E, R2 };
    GemmBatch gb{};
    for (int pp = 0; pp < 3; ++pp)
      for (int h = 0; h < 2; ++h) {
        GemmDesc d{};
        d.A0 = ap[pp] + h * 2048; d.A1 = d.A0; d.A2 = d.A0;
        d.B0 = bp[pp] + h * 2048; d.B1 = d.B0; d.B2 = d.B0;
        d.nseg = 1; d.segK = 2048; d.lda = BDIM; d.ldb = BDIM;
        d.out32a = part + (size_t)(pp * 2 + h) * 1048576;
        gb.d[pp * 2 + h] = d;
      }
    for (int i = 0; i <= 6; ++i) gb.start[i] = i * 64;
    gb.n = 6;
    gemm_k<<<384, 256, 0, stream>>>(gb);
  }

  // ---- s10-s13: heb fix, y assembly, tanh means ----
  hebfix_k<<<512, 256, 0, stream>>>(hebin[5], part, hebout[5]);
  yassm_k<<<2048, 256, 0, stream>>>(F3, out);
  tanhcol_k<<<16, 256, 0, stream>>>(F3, wpart, dpart);
  finalize_k<<<1, 64, 0, stream>>>(wpart, dpart, out, out_size);
}

// Round 4
// 712.701 us; speedup vs baseline: 1.3653x; 1.0277x over previous
//
#include <hip/hip_runtime.h>
#include <stdint.h>

#define ALPHA 0.3f
#define CLAMPV 0.3f
#define BDIM 4096
#define NDIM 1024

typedef float f32x4 __attribute__((ext_vector_type(4)));
typedef __bf16 bf16x8 __attribute__((ext_vector_type(8)));

union U16x8 { uint4 v; unsigned short u[8]; };

__device__ __forceinline__ float bf2f(unsigned short u) {
  union { unsigned int i; float f; } c; c.i = ((unsigned int)u) << 16; return c.f;
}
__device__ __forceinline__ unsigned short f2bf(float f) {
  union { float f; unsigned int i; } c; c.f = f;
  unsigned int u = c.i;
  unsigned int r = u + 0x7FFFu + ((u >> 16) & 1u);
  return (unsigned short)(r >> 16);
}

// ---------------------------------------------------------------------------
__global__ __launch_bounds__(256) void fill_k(float* __restrict__ out, int n) {
  int i = blockIdx.x * 256 + threadIdx.x;
  if (i < n) out[i] = 12345.0f;
}

// ---------------------------------------------------------------------------
__global__ __launch_bounds__(256) void split_x_k(const float* __restrict__ x,
                                                 unsigned short* __restrict__ hi,
                                                 unsigned short* __restrict__ lo) {
  const size_t i0 = ((size_t)blockIdx.x * 256 + threadIdx.x) * 8;
  f32x4 a = *(const f32x4*)(x + i0);
  f32x4 b = *(const f32x4*)(x + i0 + 4);
  U16x8 h8, l8;
#pragma unroll
  for (int i = 0; i < 4; ++i) {
    unsigned short h = f2bf(a[i]); h8.u[i] = h; l8.u[i] = f2bf(a[i] - bf2f(h));
    unsigned short h2 = f2bf(b[i]); h8.u[4+i] = h2; l8.u[4+i] = f2bf(b[i] - bf2f(h2));
  }
  *(uint4*)(hi + i0) = h8.v;
  *(uint4*)(lo + i0) = l8.v;
}

// ---------------------------------------------------------------------------
// batched tiled transpose (unchanged from round 3)
// ---------------------------------------------------------------------------
struct TDesc {
  const void* in1; const void* in2; const float* Wp;
  unsigned short* out_hi; unsigned short* out_lo;
  int R, C, tilesC, mode;
};
struct TBatch { TDesc d[8]; int start[9]; int n; };

__global__ __launch_bounds__(256) void transpose_k(TBatch batch) {
  const int bid = blockIdx.x;
  int g = 0;
#pragma unroll
  for (int i = 1; i < 8; ++i)
    if (i < batch.n && bid >= batch.start[i]) g = i;
  TDesc D = batch.d[g];
  const int lt = bid - batch.start[g];
  const int trow = lt / D.tilesC;
  const int tcol = lt - trow * D.tilesC;
  const int r0 = trow * 64, c0 = tcol * 64;

  __shared__ float tile[64][65];
  const int t = threadIdx.x;
  const int sub = t >> 3, oct = t & 7;
  const float Wv = (D.mode == 2) ? *D.Wp : 0.f;

#pragma unroll
  for (int p = 0; p < 2; ++p) {
    const int rl = p * 32 + sub;
    const int cl0 = oct * 8;
    float vv[8];
    if (D.mode == 0) {
      const unsigned short* ip = (const unsigned short*)D.in1 + (size_t)(r0 + rl) * D.C + c0 + cl0;
      U16x8 tmp; tmp.v = *(const uint4*)ip;
#pragma unroll
      for (int i = 0; i < 8; ++i) vv[i] = bf2f(tmp.u[i]);
    } else {
      const float* ip = (const float*)D.in1 + (size_t)(r0 + rl) * D.C + c0 + cl0;
      f32x4 a = *(const f32x4*)ip, b = *(const f32x4*)(ip + 4);
#pragma unroll
      for (int i = 0; i < 4; ++i) { vv[i] = a[i]; vv[4+i] = b[i]; }
      if (D.mode == 2) {
        const float* ip2 = (const float*)D.in2 + (size_t)(r0 + rl) * D.C + c0 + cl0;
        f32x4 c = *(const f32x4*)ip2, d2 = *(const f32x4*)(ip2 + 4);
#pragma unroll
        for (int i = 0; i < 4; ++i) { vv[i] += Wv * c[i]; vv[4+i] += Wv * d2[i]; }
      }
    }
#pragma unroll
    for (int i = 0; i < 8; ++i) tile[cl0 + i][rl] = vv[i];
  }
  __syncthreads();
#pragma unroll
  for (int p = 0; p < 2; ++p) {
    const int cl = p * 32 + sub;
    const int rl0 = oct * 8;
    U16x8 h8, l8;
#pragma unroll
    for (int i = 0; i < 8; ++i) {
      float v = tile[cl][rl0 + i];
      unsigned short h = f2bf(v);
      h8.u[i] = h;
      l8.u[i] = f2bf(v - bf2f(h));
    }
    const size_t o = (size_t)(c0 + cl) * D.R + r0 + rl0;
    *(uint4*)(D.out_hi + o) = h8.v;
    if (D.mode != 0) *(uint4*)(D.out_lo + o) = l8.v;
  }
}

// ---------------------------------------------------------------------------
// batched MFMA GEMM, 128x128 tile, BK=32, 4 waves, split-bf16 via K-segments.
// v3: 2-phase double-buffered pipeline — stage(kt+1) issued BEFORE compute
// of kt, single __syncthreads (vmcnt(0)+barrier) per K-step. LDS 2x(8+8)KB.
// Staging: global_load_lds width=16, linear LDS; both-sides XOR swizzle.
// ---------------------------------------------------------------------------
struct GemmDesc {
  const unsigned short *A0, *A1, *A2;
  const unsigned short *B0, *B1, *B2;
  int nseg, segK, lda, ldb, accadd, pad0;
  float* out32a;
  float* out32b;
  const float* addin;
  unsigned short* sp_hi;
  unsigned short* sp_lo;
  const float* heb_in;
  float* heb_out;
};
struct GemmBatch { GemmDesc d[12]; int start[13]; int n; };

__global__ __launch_bounds__(256) void gemm_k(GemmBatch batch) {
  const int bid = blockIdx.x;
  int g = 0;
#pragma unroll
  for (int i = 1; i < 12; ++i)
    if (i < batch.n && bid >= batch.start[i]) g = i;
  GemmDesc D = batch.d[g];
  const int local = bid - batch.start[g];
  const int tm = local >> 3;       // tilesN fixed at 8 (N=1024)
  const int tn = local & 7;

  __shared__ __align__(16) unsigned short As[2][128 * 32];   // 2 x 8 KB
  __shared__ __align__(16) unsigned short Bs[2][128 * 32];   // 2 x 8 KB

  const int t = threadIdx.x;
  const int lane = t & 63;
  const int wave = t >> 6;
  const int wr = wave >> 1, wc = wave & 1;
  const int fr = lane & 15, fg = lane >> 4;

  const f32x4 vzero = {0.f, 0.f, 0.f, 0.f};
  f32x4 acc[4][4];
#pragma unroll
  for (int i = 0; i < 4; ++i)
#pragma unroll
    for (int j = 0; j < 4; ++j) acc[i][j] = vzero;

  // staging geometry: thread t owns LDS bytes [t*16, t*16+16) of each buffer
  const int sr = t >> 2;                               // row 0..63
  const int ks = ((t & 3) ^ ((sr >> 1) & 3)) * 8;      // swizzled k-elem offset

  // fragment ds_read byte offsets (K-invariant, swizzled, within one buffer)
  int aoff[4], boff[4];
#pragma unroll
  for (int i = 0; i < 4; ++i) {
    const int ra = wr * 64 + i * 16 + fr;
    aoff[i] = ra * 64 + ((fg ^ ((ra >> 1) & 3)) << 4);
    const int rb = wc * 64 + i * 16 + fr;
    boff[i] = rb * 64 + ((fg ^ ((rb >> 1) & 3)) << 4);
  }

  const size_t arow0 = (size_t)(tm * 128 + sr) * D.lda + ks;
  const size_t arow1 = (size_t)(tm * 128 + sr + 64) * D.lda + ks;
  const size_t brow0 = (size_t)(tn * 128 + sr) * D.ldb + ks;
  const size_t brow1 = (size_t)(tn * 128 + sr + 64) * D.ldb + ks;
  const int kpseg = D.segK >> 5;
  const int ktot = D.nseg * kpseg;

  auto stage = [&](int kt, int b) {
    const int seg = (kt >= kpseg) + (kt >= 2 * kpseg);
    const int kb = (kt - seg * kpseg) << 5;
    const unsigned short* Ap = (seg == 0) ? D.A0 : ((seg == 1) ? D.A1 : D.A2);
    const unsigned short* Bp = (seg == 0) ? D.B0 : ((seg == 1) ? D.B1 : D.B2);
    unsigned short* AsW = &As[b][0] + wave * 512;
    unsigned short* BsW = &Bs[b][0] + wave * 512;
    __builtin_amdgcn_global_load_lds(
        (const __attribute__((address_space(1))) void*)(Ap + arow0 + kb),
        (__attribute__((address_space(3))) void*)AsW, 16, 0, 0);
    __builtin_amdgcn_global_load_lds(
        (const __attribute__((address_space(1))) void*)(Ap + arow1 + kb),
        (__attribute__((address_space(3))) void*)(AsW + 2048), 16, 0, 0);
    __builtin_amdgcn_global_load_lds(
        (const __attribute__((address_space(1))) void*)(Bp + brow0 + kb),
        (__attribute__((address_space(3))) void*)BsW, 16, 0, 0);
    __builtin_amdgcn_global_load_lds(
        (const __attribute__((address_space(1))) void*)(Bp + brow1 + kb),
        (__attribute__((address_space(3))) void*)(BsW + 2048), 16, 0, 0);
  };

  stage(0, 0);
  __syncthreads();                       // drain stage(0), rendezvous
  int buf = 0;
  for (int kt = 0; kt < ktot; ++kt) {
    if (kt + 1 < ktot) stage(kt + 1, buf ^ 1);   // prefetch next tile
    const char* Asb = (const char*)&As[buf][0];
    const char* Bsb = (const char*)&Bs[buf][0];
    bf16x8 af[4], bfr[4];
#pragma unroll
    for (int i = 0; i < 4; ++i) af[i] = *(const bf16x8*)(Asb + aoff[i]);
#pragma unroll
    for (int j = 0; j < 4; ++j) bfr[j] = *(const bf16x8*)(Bsb + boff[j]);
#pragma unroll
    for (int i = 0; i < 4; ++i)
#pragma unroll
      for (int j = 0; j < 4; ++j)
        acc[i][j] = __builtin_amdgcn_mfma_f32_16x16x32_bf16(af[i], bfr[j], acc[i][j], 0, 0, 0);
    __syncthreads();                     // drains prefetch; all reads of buf done
    buf ^= 1;
  }

  const int grb = tm * 128 + wr * 64 + fg * 4;
  const int gcb = tn * 128 + wc * 64 + fr;
#pragma unroll
  for (int i = 0; i < 4; ++i) {
#pragma unroll
    for (int j = 0; j < 4; ++j) {
      const int gc = gcb + j * 16;
#pragma unroll
      for (int r = 0; r < 4; ++r) {
        const int gr = grb + i * 16 + r;
        const size_t idx = (size_t)gr * NDIM + gc;
        const float v = acc[i][j][r];
        if (D.heb_out) {
          D.heb_out[idx] = fminf(fmaxf(D.heb_in[idx] + ALPHA * v, -CLAMPV), CLAMPV);
        } else {
          if (D.out32a) D.out32a[idx] = v;
          if (D.out32b) D.out32b[idx] = D.accadd ? (D.out32b[idx] + v) : v;
          if (D.sp_hi) {
            float rv = v + (D.addin ? D.addin[idx] : 0.f);
            rv = fmaxf(rv, 0.f);
            const unsigned short h = f2bf(rv);
            D.sp_hi[idx] = h;
            D.sp_lo[idx] = f2bf(rv - bf2f(h));
          }
        }
      }
    }
  }
}

// ---------------------------------------------------------------------------
// heb output from up to 8 split-K partials: out = clamp(heb_in + ALPHA*sum)
// ---------------------------------------------------------------------------
struct HebRed { const float* heb_in; float* out; const float* p[8]; int np; };

__global__ __launch_bounds__(256) void hebred_k(HebRed R) {
  const size_t i0 = ((size_t)blockIdx.x * 256 + threadIdx.x) * 4;
  f32x4 s = *(const f32x4*)(R.p[0] + i0);
#pragma unroll
  for (int k = 1; k < 8; ++k)
    if (k < R.np) s += *(const f32x4*)(R.p[k] + i0);
  f32x4 h = *(const f32x4*)(R.heb_in + i0);
  f32x4 o;
#pragma unroll
  for (int i = 0; i < 4; ++i) o[i] = fminf(fmaxf(h[i] + ALPHA * s[i], -CLAMPV), CLAMPV);
  *(f32x4*)(R.out + i0) = o;
}

// ---------------------------------------------------------------------------
__global__ __launch_bounds__(256) void yassm_k(const float* __restrict__ ysum,
                                               float* __restrict__ yout) {
  const int stride = gridDim.x * 256;
  for (int idx = blockIdx.x * 256 + threadIdx.x; idx < BDIM * 1022; idx += stride) {
    const int row = idx / 1022;
    const int col = idx - row * 1022;
    yout[idx] = ysum[(size_t)row * NDIM + col];
  }
}

__global__ __launch_bounds__(256) void tanhcol_k(const float* __restrict__ ysum,
                                                 float* __restrict__ wpart,
                                                 float* __restrict__ dpart) {
  const int r = blockIdx.x * 256 + threadIdx.x;
  const size_t b = (size_t)r * NDIM;
  float tw = tanhf(ysum[b + 1022]);
  float td = tanhf(ysum[b + 1021]);
#pragma unroll
  for (int o = 32; o > 0; o >>= 1) { tw += __shfl_down(tw, o); td += __shfl_down(td, o); }
  __shared__ float s1[4], s2[4];
  const int lane = threadIdx.x & 63, wv = threadIdx.x >> 6;
  if (lane == 0) { s1[wv] = tw; s2[wv] = td; }
  __syncthreads();
  if (threadIdx.x == 0) {
    wpart[blockIdx.x] = s1[0] + s1[1] + s1[2] + s1[3];
    dpart[blockIdx.x] = s2[0] + s2[1] + s2[2] + s2[3];
  }
}

__global__ void finalize_k(const float* __restrict__ wpart, const float* __restrict__ dpart,
                           float* __restrict__ out, int nout) {
  if (threadIdx.x == 0 && blockIdx.x == 0) {
    float s = 0.f, d = 0.f;
    for (int i = 0; i < 16; ++i) { s += wpart[i]; d += dpart[i]; }
    out[nout - 2] = s * (1.f / BDIM);
    out[nout - 1] = d * (1.f / BDIM);
  }
}

// ---------------------------------------------------------------------------
extern "C" void kernel_launch(void* const* d_in, const int* in_sizes, int n_in,
                              void* d_out, int out_size, void* d_ws, size_t ws_size,
                              hipStream_t stream) {
  const float* x = (const float*)d_in[0];
  const float* wbase[6]; const float* hebin[6];
  for (int i = 0; i < 6; ++i) { wbase[i] = (const float*)d_in[1 + i]; hebin[i] = (const float*)d_in[7 + i]; }
  const float* Wp = (const float*)d_in[13];
  float* out = (float*)d_out;
  const size_t YOUT = (size_t)BDIM * 1022;
  float* hebout[6];
  for (int i = 0; i < 6; ++i) hebout[i] = out + YOUT + (size_t)i * 1048576;

  // ---- workspace layout: 200 MiB, lifetime-aliased regions ----
  const size_t E = (size_t)BDIM * NDIM;          // 4194304 elements
  const size_t PAIRB = E * 4;                    // hi+lo bf16 pair (16 MiB)
  const size_t WPAIRB = (size_t)NDIM * NDIM * 4; // weight hi+lo pair (4 MiB)
  const size_t FB = E * 4;                       // f32 buffer (16 MiB)
  const size_t REQUIRED = 7 * PAIRB + 6 * WPAIRB + 4 * FB;  // 209,715,200 B

  if (ws_size < REQUIRED) {
    fill_k<<<(out_size + 255) / 256, 256, 0, stream>>>(out, out_size);
    return;
  }

  char* p = (char*)d_ws;
  auto takeB = [&](size_t n) -> char* { char* q = p; p += n; return q; };

  unsigned short* R0 = (unsigned short*)takeB(PAIRB);   // x pair -> h1 pair
  unsigned short* R1 = (unsigned short*)takeB(PAIRB);   // xT pair -> (stays xT) ... h1T pair
  unsigned short* R2 = (unsigned short*)takeB(PAIRB);   // h0 pair -> fT5 pair
  unsigned short* R3 = (unsigned short*)takeB(PAIRB);   // h0T pair
  unsigned short* R4 = (unsigned short*)takeB(PAIRB);   // fT0 -> fT2 -> h12y parts 0-3
  unsigned short* R5 = (unsigned short*)takeB(PAIRB);   // fT1 -> fT4 -> h12y parts 4-7
  unsigned short* R6 = (unsigned short*)takeB(PAIRB);   // fT3 -> h02y part2 -> wpart/dpart
  unsigned short* WThi[6]; unsigned short* WTlo[6];
  for (int i = 0; i < 6; ++i) {
    WThi[i] = (unsigned short*)takeB(WPAIRB);
    WTlo[i] = WThi[i] + (size_t)NDIM * NDIM;
  }
  float* F0 = (float*)takeB(FB);   // h0x -> h10
  float* F1 = (float*)takeB(FB);   // h1x -> y1tmp
  float* F2 = (float*)takeB(FB);   // yxtmp -> y0tmp
  float* F3 = (float*)takeB(FB);   // ysum (live to end)

  unsigned short *xhi = R0, *xlo = R0 + E;
  unsigned short *xThi = R1, *xTlo = R1 + E;             // live through s5
  unsigned short *h0hi = R2, *h0lo = R2 + E;
  unsigned short *h0Thi = R3, *h0Tlo = R3 + E;
  float* part = (float*)R4;                              // h12y: 8 x 1M f32 (R4+R5)
  float* wpart = (float*)R6; float* dpart = wpart + 64;

  // ---- s1: split x ----
  split_x_k<<<2048, 256, 0, stream>>>(x, xhi, xlo);

  // ---- s2: Weff^T splits (6) + x^T split ----
  {
    TBatch tb{};
    int s = 0;
    for (int i = 0; i < 6; ++i) {
      tb.d[i] = { wbase[i], hebin[i], Wp, WThi[i], WTlo[i], NDIM, NDIM, NDIM / 64, 2 };
      tb.start[i] = s; s += (NDIM / 64) * (NDIM / 64);
    }
    tb.d[6] = { x, nullptr, nullptr, xThi, xTlo, BDIM, NDIM, NDIM / 64, 1 };
    tb.start[6] = s; s += (BDIM / 64) * (NDIM / 64);
    tb.start[7] = s; tb.n = 7;
    transpose_k<<<s, 256, 0, stream>>>(tb);
  }

  auto fwdDesc = [&](const unsigned short* ahi, const unsigned short* alo, int wi) -> GemmDesc {
    GemmDesc d{};
    d.A0 = ahi; d.A1 = ahi; d.A2 = alo;
    d.B0 = WThi[wi]; d.B1 = WTlo[wi]; d.B2 = WThi[wi];
    d.nseg = 3; d.segK = NDIM; d.lda = NDIM; d.ldb = NDIM;
    return d;
  };
  // split-K Hebbian partial: C_part = sum of 3 terms over k-window [koff, koff+segK)
  auto hebPart = [&](const unsigned short* ahi, const unsigned short* alo,
                     const unsigned short* bhi, const unsigned short* blo,
                     int koff, int segK, float* partOut) -> GemmDesc {
    GemmDesc d{};
    d.A0 = ahi + koff; d.A1 = ahi + koff; d.A2 = alo + koff;
    d.B0 = bhi + koff; d.B1 = blo + koff; d.B2 = bhi + koff;
    d.nseg = 3; d.segK = segK; d.lda = BDIM; d.ldb = BDIM;
    d.out32a = partOut;
    return d;
  };
  auto hebRed = [&](int hi, const float* q0, const float* q1, const float* q2,
                    const float* q3, const float* q4, const float* q5,
                    const float* q6, const float* q7, int np) {
    HebRed r{};
    r.heb_in = hebin[hi]; r.out = hebout[hi];
    r.p[0]=q0; r.p[1]=q1; r.p[2]=q2; r.p[3]=q3; r.p[4]=q4; r.p[5]=q5; r.p[6]=q6; r.p[7]=q7;
    r.np = np;
    hebred_k<<<1024, 256, 0, stream>>>(r);
  };

  // ---- s3: h0x, h1x, yx  (768 blocks x 96 steps) ----
  {
    GemmBatch gb{};
    gb.d[0] = fwdDesc(xhi, xlo, 0);                       // h0x
    gb.d[0].out32a = F0; gb.d[0].sp_hi = h0hi; gb.d[0].sp_lo = h0lo;
    gb.d[1] = fwdDesc(xhi, xlo, 1);                       // h1x
    gb.d[1].out32a = F1;
    gb.d[2] = fwdDesc(xhi, xlo, 3);                       // yx
    gb.d[2].out32a = F2; gb.d[2].out32b = F3; gb.d[2].accadd = 0;
    gb.start[0] = 0; gb.start[1] = 256; gb.start[2] = 512; gb.start[3] = 768;
    gb.n = 3;
    gemm_k<<<768, 256, 0, stream>>>(gb);
  }

  // ---- s4: fT0=h0x^T, fT1=h1x^T, fT3=yx^T (splits); h0T hi/lo ----
  {
    TBatch tb{};
    tb.d[0] = { F0, nullptr, nullptr, R4, R4 + E, BDIM, NDIM, NDIM / 64, 1 };
    tb.d[1] = { F1, nullptr, nullptr, R5, R5 + E, BDIM, NDIM, NDIM / 64, 1 };
    tb.d[2] = { F2, nullptr, nullptr, R6, R6 + E, BDIM, NDIM, NDIM / 64, 1 };
    tb.d[3] = { h0hi, nullptr, nullptr, h0Thi, nullptr, BDIM, NDIM, NDIM / 64, 0 };
    tb.d[4] = { h0lo, nullptr, nullptr, h0Tlo, nullptr, BDIM, NDIM, NDIM / 64, 0 };
    for (int i = 0; i < 6; ++i) tb.start[i] = i * 1024;
    tb.n = 5;
    transpose_k<<<5120, 256, 0, stream>>>(tb);
  }

  // ---- s5: heb{x2h0,x2h1,x2y} 2-way split-K (long blocks first) + h10, y0 ----
  // partial slots: WT[0],WT[1],WT[3] regions (dead) + hebout[0],[1],[3] (scratch)
  {
    float* px0a = (float*)WThi[0]; float* px0b = hebout[0];
    float* px1a = (float*)WThi[1]; float* px1b = hebout[1];
    float* pxya = (float*)WThi[3]; float* pxyb = hebout[3];
    GemmBatch gb{};
    gb.d[0] = hebPart(xThi, xTlo, R4, R4 + E, 0,    2048, px0a);  // x2h0 half 0
    gb.d[1] = hebPart(xThi, xTlo, R4, R4 + E, 2048, 2048, px0b);  // x2h0 half 1
    gb.d[2] = hebPart(xThi, xTlo, R5, R5 + E, 0,    2048, px1a);  // x2h1
    gb.d[3] = hebPart(xThi, xTlo, R5, R5 + E, 2048, 2048, px1b);
    gb.d[4] = hebPart(xThi, xTlo, R6, R6 + E, 0,    2048, pxya);  // x2y
    gb.d[5] = hebPart(xThi, xTlo, R6, R6 + E, 2048, 2048, pxyb);
    gb.d[6] = fwdDesc(h0hi, h0lo, 2);                     // h1_0
    gb.d[6].out32a = F0; gb.d[6].addin = F1; gb.d[6].sp_hi = R0; gb.d[6].sp_lo = R0 + E;
    gb.d[7] = fwdDesc(h0hi, h0lo, 4);                     // y0
    gb.d[7].out32a = F2; gb.d[7].out32b = F3; gb.d[7].accadd = 1;
    for (int i = 0; i < 6; ++i) gb.start[i] = i * 64;
    gb.start[6] = 384; gb.start[7] = 640; gb.start[8] = 896;
    gb.n = 8;
    gemm_k<<<896, 256, 0, stream>>>(gb);
    hebRed(0, px0a, px0b, 0,0,0,0,0,0, 2);
    hebRed(1, px1a, px1b, 0,0,0,0,0,0, 2);
    hebRed(3, pxya, pxyb, 0,0,0,0,0,0, 2);
  }

  // ---- s6: fT2=h10^T, fT4=y0^T (splits); h1T hi/lo into R1... wait R1 = xT
  // xT is DEAD after s5 -> h1T goes into R1 (as before).
  {
    TBatch tb{};
    tb.d[0] = { F0, nullptr, nullptr, R4, R4 + E, BDIM, NDIM, NDIM / 64, 1 };
    tb.d[1] = { F2, nullptr, nullptr, R5, R5 + E, BDIM, NDIM, NDIM / 64, 1 };
    tb.d[2] = { R0, nullptr, nullptr, R1, nullptr, BDIM, NDIM, NDIM / 64, 0 };
    tb.d[3] = { R0 + E, nullptr, nullptr, R1 + E, nullptr, BDIM, NDIM, NDIM / 64, 0 };
    for (int i = 0; i < 5; ++i) tb.start[i] = i * 1024;
    tb.n = 4;
    transpose_k<<<4096, 256, 0, stream>>>(tb);
  }

  // ---- s7: heb{h02h1,h02y} 4-way split-K + y1  (768 blocks x 96 steps) ----
  // partial slots: WT[0],WT[1],WT[2] + hebout[2]; WT[3],WT[4],R6 + hebout[4]
  {
    float* pa[4] = { (float*)WThi[0], (float*)WThi[1], (float*)WThi[2], hebout[2] };
    float* pb[4] = { (float*)WThi[3], (float*)WThi[4], (float*)R6,      hebout[4] };
    GemmBatch gb{};
    for (int h = 0; h < 4; ++h) {
      gb.d[h]     = hebPart(h0Thi, h0Tlo, R4, R4 + E, h * 1024, 1024, pa[h]); // h02h1
      gb.d[4 + h] = hebPart(h0Thi, h0Tlo, R5, R5 + E, h * 1024, 1024, pb[h]); // h02y
    }
    gb.d[8] = fwdDesc(R0, R0 + E, 5);                     // y1 (A = h1 pair)
    gb.d[8].out32a = F1; gb.d[8].out32b = F3; gb.d[8].accadd = 1;
    for (int i = 0; i < 8; ++i) gb.start[i] = i * 64;
    gb.start[8] = 512; gb.start[9] = 768;
    gb.n = 9;
    gemm_k<<<768, 256, 0, stream>>>(gb);
    hebRed(2, pa[0], pa[1], pa[2], pa[3], 0,0,0,0, 4);
    hebRed(4, pb[0], pb[1], pb[2], pb[3], 0,0,0,0, 4);
  }

  // ---- s8: fT5 = y1^T split into R2 ----
  {
    TBatch tb{};
    tb.d[0] = { F1, nullptr, nullptr, R2, R2 + E, BDIM, NDIM, NDIM / 64, 1 };
    tb.start[0] = 0; tb.start[1] = 1024; tb.n = 1;
    transpose_k<<<1024, 256, 0, stream>>>(tb);
  }

  // ---- s9: heb_h12y 8-way split-K (512 blocks x 48 steps) ----
  // partials: 8 x 1M f32 contiguous in R4+R5 (fT2/fT4 dead after s7)
  {
    GemmBatch gb{};
    for (int h = 0; h < 8; ++h)
      gb.d[h] = hebPart(R1, R1 + E, R2, R2 + E, h * 512, 512, part + (size_t)h * 1048576);
    for (int i = 0; i <= 8; ++i) gb.start[i] = i * 64;
    gb.n = 8;
    gemm_k<<<512, 256, 0, stream>>>(gb);
    hebRed(5, part, part + 1048576, part + 2097152, part + 3145728,
           part + 4194304, part + 5242880, part + 6291456, part + 7340032, 8);
  }

  // ---- s10: y assembly, tanh means ----
  yassm_k<<<2048, 256, 0, stream>>>(F3, out);
  tanhcol_k<<<16, 256, 0, stream>>>(F3, wpart, dpart);
  finalize_k<<<1, 64, 0, stream>>>(wpart, dpart, out, out_size);
}

// Round 5
// 502.593 us; speedup vs baseline: 1.9360x; 1.4180x over previous
//
#include <hip/hip_runtime.h>
#include <stdint.h>

#define ALPHA 0.3f
#define CLAMPV 0.3f
#define BDIM 4096
#define NDIM 1024

typedef float f32x4 __attribute__((ext_vector_type(4)));
typedef __bf16 bf16x8 __attribute__((ext_vector_type(8)));

union U16x8 { uint4 v; unsigned short u[8]; };

__device__ __forceinline__ float bf2f(unsigned short u) {
  union { unsigned int i; float f; } c; c.i = ((unsigned int)u) << 16; return c.f;
}
__device__ __forceinline__ unsigned short f2bf(float f) {
  union { float f; unsigned int i; } c; c.f = f;
  unsigned int u = c.i;
  unsigned int r = u + 0x7FFFu + ((u >> 16) & 1u);
  return (unsigned short)(r >> 16);
}

// ---------------------------------------------------------------------------
__global__ __launch_bounds__(256) void fill_k(float* __restrict__ out, int n) {
  int i = blockIdx.x * 256 + threadIdx.x;
  if (i < n) out[i] = 12345.0f;
}

// ---------------------------------------------------------------------------
__global__ __launch_bounds__(256) void split_x_k(const float* __restrict__ x,
                                                 unsigned short* __restrict__ hi,
                                                 unsigned short* __restrict__ lo) {
  const size_t i0 = ((size_t)blockIdx.x * 256 + threadIdx.x) * 8;
  f32x4 a = *(const f32x4*)(x + i0);
  f32x4 b = *(const f32x4*)(x + i0 + 4);
  U16x8 h8, l8;
#pragma unroll
  for (int i = 0; i < 4; ++i) {
    unsigned short h = f2bf(a[i]); h8.u[i] = h; l8.u[i] = f2bf(a[i] - bf2f(h));
    unsigned short h2 = f2bf(b[i]); h8.u[4+i] = h2; l8.u[4+i] = f2bf(b[i] - bf2f(h2));
  }
  *(uint4*)(hi + i0) = h8.v;
  *(uint4*)(lo + i0) = l8.v;
}

// ---------------------------------------------------------------------------
// batched tiled transpose (unchanged)
// ---------------------------------------------------------------------------
struct TDesc {
  const void* in1; const void* in2; const float* Wp;
  unsigned short* out_hi; unsigned short* out_lo;
  int R, C, tilesC, mode;
};
struct TBatch { TDesc d[8]; int start[9]; int n; };

__global__ __launch_bounds__(256) void transpose_k(TBatch batch) {
  const int bid = blockIdx.x;
  int g = 0;
#pragma unroll
  for (int i = 1; i < 8; ++i)
    if (i < batch.n && bid >= batch.start[i]) g = i;
  TDesc D = batch.d[g];
  const int lt = bid - batch.start[g];
  const int trow = lt / D.tilesC;
  const int tcol = lt - trow * D.tilesC;
  const int r0 = trow * 64, c0 = tcol * 64;

  __shared__ float tile[64][65];
  const int t = threadIdx.x;
  const int sub = t >> 3, oct = t & 7;
  const float Wv = (D.mode == 2) ? *D.Wp : 0.f;

#pragma unroll
  for (int p = 0; p < 2; ++p) {
    const int rl = p * 32 + sub;
    const int cl0 = oct * 8;
    float vv[8];
    if (D.mode == 0) {
      const unsigned short* ip = (const unsigned short*)D.in1 + (size_t)(r0 + rl) * D.C + c0 + cl0;
      U16x8 tmp; tmp.v = *(const uint4*)ip;
#pragma unroll
      for (int i = 0; i < 8; ++i) vv[i] = bf2f(tmp.u[i]);
    } else {
      const float* ip = (const float*)D.in1 + (size_t)(r0 + rl) * D.C + c0 + cl0;
      f32x4 a = *(const f32x4*)ip, b = *(const f32x4*)(ip + 4);
#pragma unroll
      for (int i = 0; i < 4; ++i) { vv[i] = a[i]; vv[4+i] = b[i]; }
      if (D.mode == 2) {
        const float* ip2 = (const float*)D.in2 + (size_t)(r0 + rl) * D.C + c0 + cl0;
        f32x4 c = *(const f32x4*)ip2, d2 = *(const f32x4*)(ip2 + 4);
#pragma unroll
        for (int i = 0; i < 4; ++i) { vv[i] += Wv * c[i]; vv[4+i] += Wv * d2[i]; }
      }
    }
#pragma unroll
    for (int i = 0; i < 8; ++i) tile[cl0 + i][rl] = vv[i];
  }
  __syncthreads();
#pragma unroll
  for (int p = 0; p < 2; ++p) {
    const int cl = p * 32 + sub;
    const int rl0 = oct * 8;
    U16x8 h8, l8;
#pragma unroll
    for (int i = 0; i < 8; ++i) {
      float v = tile[cl][rl0 + i];
      unsigned short h = f2bf(v);
      h8.u[i] = h;
      l8.u[i] = f2bf(v - bf2f(h));
    }
    const size_t o = (size_t)(c0 + cl) * D.R + r0 + rl0;
    *(uint4*)(D.out_hi + o) = h8.v;
    if (D.mode != 0) *(uint4*)(D.out_lo + o) = l8.v;
  }
}

// ---------------------------------------------------------------------------
// batched MFMA GEMM v4: 128x128 tile, BK=64, 4 waves, fused split-bf16.
//   phase 0: stage {Ahi, Bhi, Blo} (48KB) -> Ahi*Bhi + Ahi*Blo  (64 MFMA/wave)
//   phase 1: stage {Alo, Bhi}             -> Alo*Bhi            (32 MFMA/wave)
// Single-buffered, one stage+drain per BK=64 step (32 drains/K=1024-block
// vs 96 in v2/v3). Linear LDS (128B rows) + 3-bit XOR swizzle both sides.
// ---------------------------------------------------------------------------
struct GemmDesc {
  const unsigned short *Ahi, *Alo, *Bhi, *Blo;
  int lda, ldb, nk, accadd;     // nk = K/64 steps per phase
  float* out32a;
  float* out32b;
  const float* addin;
  unsigned short* sp_hi;
  unsigned short* sp_lo;
  const float* heb_in;
  float* heb_out;
};
struct GemmBatch { GemmDesc d[12]; int start[13]; int n; };

__global__ __launch_bounds__(256) void gemm_k(GemmBatch batch) {
  const int bid = blockIdx.x;
  int g = 0;
#pragma unroll
  for (int i = 1; i < 12; ++i)
    if (i < batch.n && bid >= batch.start[i]) g = i;
  GemmDesc D = batch.d[g];
  const int local = bid - batch.start[g];
  const int tm = local >> 3;        // tilesN fixed at 8 (N=1024)
  const int tn = local & 7;

  __shared__ __align__(16) unsigned short As[128 * 64];    // 16 KB
  __shared__ __align__(16) unsigned short BsH[128 * 64];   // 16 KB
  __shared__ __align__(16) unsigned short BsL[128 * 64];   // 16 KB

  const int t = threadIdx.x;
  const int lane = t & 63;
  const int wave = t >> 6;
  const int wr = wave >> 1, wc = wave & 1;
  const int fr = lane & 15, fg = lane >> 4;

  const f32x4 vzero = {0.f, 0.f, 0.f, 0.f};
  f32x4 acc[4][4];
#pragma unroll
  for (int i = 0; i < 4; ++i)
#pragma unroll
    for (int j = 0; j < 4; ++j) acc[i][j] = vzero;

  // staging geometry: rows are 128B; thread t covers rows srow+32q, bytes
  // [scolB, scolB+16) where scolB is the 3-bit XOR pre-swizzled column.
  const int srow = t >> 3;                                   // 0..31
  const int scolB = ((t & 7) << 4) ^ ((srow & 7) << 4);      // bytes in row
  const int scolE = scolB >> 1;                              // elems

  // fragment ds_read byte offsets (s=0 slice; slice 1 = ^0x40)
  int aoff[4], boff[4];
#pragma unroll
  for (int i = 0; i < 4; ++i) {
    const int ra = wr * 64 + i * 16 + fr;
    aoff[i] = ra * 128 + ((fg << 4) ^ ((ra & 7) << 4));
    const int rb = wc * 64 + i * 16 + fr;
    boff[i] = rb * 128 + ((fg << 4) ^ ((rb & 7) << 4));
  }
  const char* Asb = (const char*)As;
  const char* BsHb = (const char*)BsH;
  const char* BsLb = (const char*)BsL;

  const size_t arow = (size_t)(tm * 128 + srow) * D.lda + scolE;
  const size_t brow = (size_t)(tn * 128 + srow) * D.ldb + scolE;
  const size_t astep = (size_t)32 * D.lda;
  const size_t bstep = (size_t)32 * D.ldb;

#pragma unroll 1
  for (int ph = 0; ph < 2; ++ph) {
    const unsigned short* Ap = ph ? D.Alo : D.Ahi;
#pragma unroll 1
    for (int kt = 0; kt < D.nk; ++kt) {
      const int kb = kt << 6;   // k-elem offset
      // ---- stage (12 loads phase0, 8 loads phase1) ----
#pragma unroll
      for (int q = 0; q < 4; ++q) {
        __builtin_amdgcn_global_load_lds(
            (const __attribute__((address_space(1))) void*)(Ap + arow + q * astep + kb),
            (__attribute__((address_space(3))) void*)(As + q * 2048 + wave * 512), 16, 0, 0);
        __builtin_amdgcn_global_load_lds(
            (const __attribute__((address_space(1))) void*)(D.Bhi + brow + q * bstep + kb),
            (__attribute__((address_space(3))) void*)(BsH + q * 2048 + wave * 512), 16, 0, 0);
      }
      if (ph == 0) {
#pragma unroll
        for (int q = 0; q < 4; ++q)
          __builtin_amdgcn_global_load_lds(
              (const __attribute__((address_space(1))) void*)(D.Blo + brow + q * bstep + kb),
              (__attribute__((address_space(3))) void*)(BsL + q * 2048 + wave * 512), 16, 0, 0);
      }
      __syncthreads();           // drain stage, rendezvous
      // ---- compute: 2 k-slices of 32 ----
#pragma unroll
      for (int s = 0; s < 2; ++s) {
        const int sx = s << 6;
        bf16x8 af[4];
#pragma unroll
        for (int i = 0; i < 4; ++i) af[i] = *(const bf16x8*)(Asb + (aoff[i] ^ sx));
#pragma unroll
        for (int j = 0; j < 4; ++j) {
          const bf16x8 bh = *(const bf16x8*)(BsHb + (boff[j] ^ sx));
#pragma unroll
          for (int i = 0; i < 4; ++i)
            acc[i][j] = __builtin_amdgcn_mfma_f32_16x16x32_bf16(af[i], bh, acc[i][j], 0, 0, 0);
          if (ph == 0) {
            const bf16x8 bl = *(const bf16x8*)(BsLb + (boff[j] ^ sx));
#pragma unroll
            for (int i = 0; i < 4; ++i)
              acc[i][j] = __builtin_amdgcn_mfma_f32_16x16x32_bf16(af[i], bl, acc[i][j], 0, 0, 0);
          }
        }
      }
      __syncthreads();           // all reads done before next stage
    }
  }

  const int grb = tm * 128 + wr * 64 + fg * 4;
  const int gcb = tn * 128 + wc * 64 + fr;
#pragma unroll
  for (int i = 0; i < 4; ++i) {
#pragma unroll
    for (int j = 0; j < 4; ++j) {
      const int gc = gcb + j * 16;
#pragma unroll
      for (int r = 0; r < 4; ++r) {
        const int gr = grb + i * 16 + r;
        const size_t idx = (size_t)gr * NDIM + gc;
        const float v = acc[i][j][r];
        if (D.heb_out) {
          D.heb_out[idx] = fminf(fmaxf(D.heb_in[idx] + ALPHA * v, -CLAMPV), CLAMPV);
        } else {
          if (D.out32a) D.out32a[idx] = v;
          if (D.out32b) D.out32b[idx] = D.accadd ? (D.out32b[idx] + v) : v;
          if (D.sp_hi) {
            float rv = v + (D.addin ? D.addin[idx] : 0.f);
            rv = fmaxf(rv, 0.f);
            const unsigned short h = f2bf(rv);
            D.sp_hi[idx] = h;
            D.sp_lo[idx] = f2bf(rv - bf2f(h));
          }
        }
      }
    }
  }
}

// ---------------------------------------------------------------------------
// heb output from up to 8 split-K partials: out = clamp(heb_in + ALPHA*sum)
// ---------------------------------------------------------------------------
struct HebRed { const float* heb_in; float* out; const float* p[8]; int np; };

__global__ __launch_bounds__(256) void hebred_k(HebRed R) {
  const size_t i0 = ((size_t)blockIdx.x * 256 + threadIdx.x) * 4;
  f32x4 s = *(const f32x4*)(R.p[0] + i0);
#pragma unroll
  for (int k = 1; k < 8; ++k)
    if (k < R.np) s += *(const f32x4*)(R.p[k] + i0);
  f32x4 h = *(const f32x4*)(R.heb_in + i0);
  f32x4 o;
#pragma unroll
  for (int i = 0; i < 4; ++i) o[i] = fminf(fmaxf(h[i] + ALPHA * s[i], -CLAMPV), CLAMPV);
  *(f32x4*)(R.out + i0) = o;
}

// ---------------------------------------------------------------------------
__global__ __launch_bounds__(256) void yassm_k(const float* __restrict__ ysum,
                                               float* __restrict__ yout) {
  const int stride = gridDim.x * 256;
  for (int idx = blockIdx.x * 256 + threadIdx.x; idx < BDIM * 1022; idx += stride) {
    const int row = idx / 1022;
    const int col = idx - row * 1022;
    yout[idx] = ysum[(size_t)row * NDIM + col];
  }
}

__global__ __launch_bounds__(256) void tanhcol_k(const float* __restrict__ ysum,
                                                 float* __restrict__ wpart,
                                                 float* __restrict__ dpart) {
  const int r = blockIdx.x * 256 + threadIdx.x;
  const size_t b = (size_t)r * NDIM;
  float tw = tanhf(ysum[b + 1022]);
  float td = tanhf(ysum[b + 1021]);
#pragma unroll
  for (int o = 32; o > 0; o >>= 1) { tw += __shfl_down(tw, o); td += __shfl_down(td, o); }
  __shared__ float s1[4], s2[4];
  const int lane = threadIdx.x & 63, wv = threadIdx.x >> 6;
  if (lane == 0) { s1[wv] = tw; s2[wv] = td; }
  __syncthreads();
  if (threadIdx.x == 0) {
    wpart[blockIdx.x] = s1[0] + s1[1] + s1[2] + s1[3];
    dpart[blockIdx.x] = s2[0] + s2[1] + s2[2] + s2[3];
  }
}

__global__ void finalize_k(const float* __restrict__ wpart, const float* __restrict__ dpart,
                           float* __restrict__ out, int nout) {
  if (threadIdx.x == 0 && blockIdx.x == 0) {
    float s = 0.f, d = 0.f;
    for (int i = 0; i < 16; ++i) { s += wpart[i]; d += dpart[i]; }
    out[nout - 2] = s * (1.f / BDIM);
    out[nout - 1] = d * (1.f / BDIM);
  }
}

// ---------------------------------------------------------------------------
extern "C" void kernel_launch(void* const* d_in, const int* in_sizes, int n_in,
                              void* d_out, int out_size, void* d_ws, size_t ws_size,
                              hipStream_t stream) {
  const float* x = (const float*)d_in[0];
  const float* wbase[6]; const float* hebin[6];
  for (int i = 0; i < 6; ++i) { wbase[i] = (const float*)d_in[1 + i]; hebin[i] = (const float*)d_in[7 + i]; }
  const float* Wp = (const float*)d_in[13];
  float* out = (float*)d_out;
  const size_t YOUT = (size_t)BDIM * 1022;
  float* hebout[6];
  for (int i = 0; i < 6; ++i) hebout[i] = out + YOUT + (size_t)i * 1048576;

  // ---- workspace layout: 200 MiB, lifetime-aliased regions ----
  const size_t E = (size_t)BDIM * NDIM;
  const size_t PAIRB = E * 4;                    // hi+lo bf16 pair (16 MiB)
  const size_t WPAIRB = (size_t)NDIM * NDIM * 4; // weight hi+lo pair (4 MiB)
  const size_t FB = E * 4;                       // f32 buffer (16 MiB)
  const size_t REQUIRED = 7 * PAIRB + 6 * WPAIRB + 4 * FB;

  if (ws_size < REQUIRED) {
    fill_k<<<(out_size + 255) / 256, 256, 0, stream>>>(out, out_size);
    return;
  }

  char* p = (char*)d_ws;
  auto takeB = [&](size_t n) -> char* { char* q = p; p += n; return q; };

  unsigned short* R0 = (unsigned short*)takeB(PAIRB);   // x pair -> h1 pair
  unsigned short* R1 = (unsigned short*)takeB(PAIRB);   // xT pair -> h1T pair
  unsigned short* R2 = (unsigned short*)takeB(PAIRB);   // h0 pair -> fT5 pair
  unsigned short* R3 = (unsigned short*)takeB(PAIRB);   // h0T pair
  unsigned short* R4 = (unsigned short*)takeB(PAIRB);   // fT0 -> fT2 -> h12y parts 0-3
  unsigned short* R5 = (unsigned short*)takeB(PAIRB);   // fT1 -> fT4 -> h12y parts 4-7
  unsigned short* R6 = (unsigned short*)takeB(PAIRB);   // fT3 -> h02y parts -> wpart
  unsigned short* WThi[6]; unsigned short* WTlo[6];
  for (int i = 0; i < 6; ++i) {
    WThi[i] = (unsigned short*)takeB(WPAIRB);
    WTlo[i] = WThi[i] + (size_t)NDIM * NDIM;
  }
  float* F0 = (float*)takeB(FB);   // h0x -> h10
  float* F1 = (float*)takeB(FB);   // h1x -> y1tmp
  float* F2 = (float*)takeB(FB);   // yxtmp -> y0tmp
  float* F3 = (float*)takeB(FB);   // ysum (live to end)

  unsigned short *xhi = R0, *xlo = R0 + E;
  unsigned short *xThi = R1, *xTlo = R1 + E;
  unsigned short *h0hi = R2, *h0lo = R2 + E;
  unsigned short *h0Thi = R3, *h0Tlo = R3 + E;
  float* part = (float*)R4;        // h12y: 8 x 1M f32 spans R4+R5
  float* wpart = (float*)R6; float* dpart = wpart + 64;

  // ---- s1: split x ----
  split_x_k<<<2048, 256, 0, stream>>>(x, xhi, xlo);

  // ---- s2: Weff^T splits (6) + x^T split ----
  {
    TBatch tb{};
    int s = 0;
    for (int i = 0; i < 6; ++i) {
      tb.d[i] = { wbase[i], hebin[i], Wp, WThi[i], WTlo[i], NDIM, NDIM, NDIM / 64, 2 };
      tb.start[i] = s; s += (NDIM / 64) * (NDIM / 64);
    }
    tb.d[6] = { x, nullptr, nullptr, xThi, xTlo, BDIM, NDIM, NDIM / 64, 1 };
    tb.start[6] = s; s += (BDIM / 64) * (NDIM / 64);
    tb.start[7] = s; tb.n = 7;
    transpose_k<<<s, 256, 0, stream>>>(tb);
  }

  auto fwdDesc = [&](const unsigned short* ahi, const unsigned short* alo, int wi) -> GemmDesc {
    GemmDesc d{};
    d.Ahi = ahi; d.Alo = alo; d.Bhi = WThi[wi]; d.Blo = WTlo[wi];
    d.lda = NDIM; d.ldb = NDIM; d.nk = NDIM / 64;
    return d;
  };
  auto hebPart = [&](const unsigned short* ahi, const unsigned short* alo,
                     const unsigned short* bhi, const unsigned short* blo,
                     int koff, int klen, float* partOut) -> GemmDesc {
    GemmDesc d{};
    d.Ahi = ahi + koff; d.Alo = alo + koff;
    d.Bhi = bhi + koff; d.Blo = blo + koff;
    d.lda = BDIM; d.ldb = BDIM; d.nk = klen / 64;
    d.out32a = partOut;
    return d;
  };
  auto hebRed = [&](int hi, const float* q0, const float* q1, const float* q2,
                    const float* q3, const float* q4, const float* q5,
                    const float* q6, const float* q7, int np) {
    HebRed r{};
    r.heb_in = hebin[hi]; r.out = hebout[hi];
    r.p[0]=q0; r.p[1]=q1; r.p[2]=q2; r.p[3]=q3; r.p[4]=q4; r.p[5]=q5; r.p[6]=q6; r.p[7]=q7;
    r.np = np;
    hebred_k<<<1024, 256, 0, stream>>>(r);
  };

  // ---- s3: h0x, h1x, yx  (768 blocks = 3/CU, 32 steps each) ----
  {
    GemmBatch gb{};
    gb.d[0] = fwdDesc(xhi, xlo, 0);
    gb.d[0].out32a = F0; gb.d[0].sp_hi = h0hi; gb.d[0].sp_lo = h0lo;
    gb.d[1] = fwdDesc(xhi, xlo, 1);
    gb.d[1].out32a = F1;
    gb.d[2] = fwdDesc(xhi, xlo, 3);
    gb.d[2].out32a = F2; gb.d[2].out32b = F3; gb.d[2].accadd = 0;
    gb.start[0] = 0; gb.start[1] = 256; gb.start[2] = 512; gb.start[3] = 768;
    gb.n = 3;
    gemm_k<<<768, 256, 0, stream>>>(gb);
  }

  // ---- s4: fT0=h0x^T, fT1=h1x^T, fT3=yx^T (splits); h0T hi/lo ----
  {
    TBatch tb{};
    tb.d[0] = { F0, nullptr, nullptr, R4, R4 + E, BDIM, NDIM, NDIM / 64, 1 };
    tb.d[1] = { F1, nullptr, nullptr, R5, R5 + E, BDIM, NDIM, NDIM / 64, 1 };
    tb.d[2] = { F2, nullptr, nullptr, R6, R6 + E, BDIM, NDIM, NDIM / 64, 1 };
    tb.d[3] = { h0hi, nullptr, nullptr, h0Thi, nullptr, BDIM, NDIM, NDIM / 64, 0 };
    tb.d[4] = { h0lo, nullptr, nullptr, h0Tlo, nullptr, BDIM, NDIM, NDIM / 64, 0 };
    for (int i = 0; i < 6; ++i) tb.start[i] = i * 1024;
    tb.n = 5;
    transpose_k<<<5120, 256, 0, stream>>>(tb);
  }

  // ---- s5: heb{x2h0,x2h1,x2y} 2-way split-K + h10, y0  (896 blocks) ----
  {
    float* px0a = (float*)WThi[0]; float* px0b = hebout[0];
    float* px1a = (float*)WThi[1]; float* px1b = hebout[1];
    float* pxya = (float*)WThi[3]; float* pxyb = hebout[3];
    GemmBatch gb{};
    gb.d[0] = hebPart(xThi, xTlo, R4, R4 + E, 0,    2048, px0a);
    gb.d[1] = hebPart(xThi, xTlo, R4, R4 + E, 2048, 2048, px0b);
    gb.d[2] = hebPart(xThi, xTlo, R5, R5 + E, 0,    2048, px1a);
    gb.d[3] = hebPart(xThi, xTlo, R5, R5 + E, 2048, 2048, px1b);
    gb.d[4] = hebPart(xThi, xTlo, R6, R6 + E, 0,    2048, pxya);
    gb.d[5] = hebPart(xThi, xTlo, R6, R6 + E, 2048, 2048, pxyb);
    gb.d[6] = fwdDesc(h0hi, h0lo, 2);                     // h1_0
    gb.d[6].out32a = F0; gb.d[6].addin = F1; gb.d[6].sp_hi = R0; gb.d[6].sp_lo = R0 + E;
    gb.d[7] = fwdDesc(h0hi, h0lo, 4);                     // y0
    gb.d[7].out32a = F2; gb.d[7].out32b = F3; gb.d[7].accadd = 1;
    for (int i = 0; i < 6; ++i) gb.start[i] = i * 64;
    gb.start[6] = 384; gb.start[7] = 640; gb.start[8] = 896;
    gb.n = 8;
    gemm_k<<<896, 256, 0, stream>>>(gb);
    hebRed(0, px0a, px0b, 0,0,0,0,0,0, 2);
    hebRed(1, px1a, px1b, 0,0,0,0,0,0, 2);
    hebRed(3, pxya, pxyb, 0,0,0,0,0,0, 2);
  }

  // ---- s6: fT2=h10^T, fT4=y0^T (splits); h1T hi/lo into R1 ----
  {
    TBatch tb{};
    tb.d[0] = { F0, nullptr, nullptr, R4, R4 + E, BDIM, NDIM, NDIM / 64, 1 };
    tb.d[1] = { F2, nullptr, nullptr, R5, R5 + E, BDIM, NDIM, NDIM / 64, 1 };
    tb.d[2] = { R0, nullptr, nullptr, R1, nullptr, BDIM, NDIM, NDIM / 64, 0 };
    tb.d[3] = { R0 + E, nullptr, nullptr, R1 + E, nullptr, BDIM, NDIM, NDIM / 64, 0 };
    for (int i = 0; i < 5; ++i) tb.start[i] = i * 1024;
    tb.n = 4;
    transpose_k<<<4096, 256, 0, stream>>>(tb);
  }

  // ---- s7: heb{h02h1,h02y} 4-way split-K + y1  (768 blocks) ----
  {
    float* pa[4] = { (float*)WThi[0], (float*)WThi[1], (float*)WThi[2], (float*)WThi[3] };
    float* pb[4] = { (float*)R6, (float*)R6 + 1048576, (float*)R6 + 2097152, (float*)R6 + 3145728 };
    GemmBatch gb{};
    for (int h = 0; h < 4; ++h) {
      gb.d[h]     = hebPart(h0Thi, h0Tlo, R4, R4 + E, h * 1024, 1024, pa[h]); // h02h1
      gb.d[4 + h] = hebPart(h0Thi, h0Tlo, R5, R5 + E, h * 1024, 1024, pb[h]); // h02y
    }
    gb.d[8] = fwdDesc(R0, R0 + E, 5);                     // y1 (A = h1 pair)
    gb.d[8].out32a = F1; gb.d[8].out32b = F3; gb.d[8].accadd = 1;
    for (int i = 0; i < 8; ++i) gb.start[i] = i * 64;
    gb.start[8] = 512; gb.start[9] = 768;
    gb.n = 9;
    gemm_k<<<768, 256, 0, stream>>>(gb);
    hebRed(2, pa[0], pa[1], pa[2], pa[3], 0,0,0,0, 4);
    hebRed(4, pb[0], pb[1], pb[2], pb[3], 0,0,0,0, 4);
  }

  // ---- s8: fT5 = y1^T split into R2 ----
  {
    TBatch tb{};
    tb.d[0] = { F1, nullptr, nullptr, R2, R2 + E, BDIM, NDIM, NDIM / 64, 1 };
    tb.start[0] = 0; tb.start[1] = 1024; tb.n = 1;
    transpose_k<<<1024, 256, 0, stream>>>(tb);
  }

  // ---- s9: heb_h12y 8-way split-K (512 blocks, 8 steps each) ----
  {
    GemmBatch gb{};
    for (int h = 0; h < 8; ++h)
      gb.d[h] = hebPart(R1, R1 + E, R2, R2 + E, h * 512, 512, part + (size_t)h * 1048576);
    for (int i = 0; i <= 8; ++i) gb.start[i] = i * 64;
    gb.n = 8;
    gemm_k<<<512, 256, 0, stream>>>(gb);
    hebRed(5, part, part + 1048576, part + 2097152, part + 3145728,
           part + 4194304, part + 5242880, part + 6291456, part + 7340032, 8);
  }

  // ---- s10: y assembly, tanh means ----
  yassm_k<<<2048, 256, 0, stream>>>(F3, out);
  tanhcol_k<<<16, 256, 0, stream>>>(F3, wpart, dpart);
  finalize_k<<<1, 64, 0, stream>>>(wpart, dpart, out, out_size);
}

// Round 6
// 502.015 us; speedup vs baseline: 1.9382x; 1.0012x over previous
//
#include <hip/hip_runtime.h>
#include <stdint.h>

#define ALPHA 0.3f
#define CLAMPV 0.3f
#define BDIM 4096
#define NDIM 1024

typedef float f32x4 __attribute__((ext_vector_type(4)));
typedef __bf16 bf16x8 __attribute__((ext_vector_type(8)));

union U16x8 { uint4 v; unsigned short u[8]; };

__device__ __forceinline__ float bf2f(unsigned short u) {
  union { unsigned int i; float f; } c; c.i = ((unsigned int)u) << 16; return c.f;
}
__device__ __forceinline__ unsigned short f2bf(float f) {
  union { float f; unsigned int i; } c; c.f = f;
  unsigned int u = c.i;
  unsigned int r = u + 0x7FFFu + ((u >> 16) & 1u);
  return (unsigned short)(r >> 16);
}

// ---------------------------------------------------------------------------
__global__ __launch_bounds__(256) void fill_k(float* __restrict__ out, int n) {
  int i = blockIdx.x * 256 + threadIdx.x;
  if (i < n) out[i] = 12345.0f;
}

// ---------------------------------------------------------------------------
__global__ __launch_bounds__(256) void split_x_k(const float* __restrict__ x,
                                                 unsigned short* __restrict__ hi,
                                                 unsigned short* __restrict__ lo) {
  const size_t i0 = ((size_t)blockIdx.x * 256 + threadIdx.x) * 8;
  f32x4 a = *(const f32x4*)(x + i0);
  f32x4 b = *(const f32x4*)(x + i0 + 4);
  U16x8 h8, l8;
#pragma unroll
  for (int i = 0; i < 4; ++i) {
    unsigned short h = f2bf(a[i]); h8.u[i] = h; l8.u[i] = f2bf(a[i] - bf2f(h));
    unsigned short h2 = f2bf(b[i]); h8.u[4+i] = h2; l8.u[4+i] = f2bf(b[i] - bf2f(h2));
  }
  *(uint4*)(hi + i0) = h8.v;
  *(uint4*)(lo + i0) = l8.v;
}

// ---------------------------------------------------------------------------
// batched tiled transpose (unchanged)
// ---------------------------------------------------------------------------
struct TDesc {
  const void* in1; const void* in2; const float* Wp;
  unsigned short* out_hi; unsigned short* out_lo;
  int R, C, tilesC, mode;
};
struct TBatch { TDesc d[8]; int start[9]; int n; };

__global__ __launch_bounds__(256) void transpose_k(TBatch batch) {
  const int bid = blockIdx.x;
  int g = 0;
#pragma unroll
  for (int i = 1; i < 8; ++i)
    if (i < batch.n && bid >= batch.start[i]) g = i;
  TDesc D = batch.d[g];
  const int lt = bid - batch.start[g];
  const int trow = lt / D.tilesC;
  const int tcol = lt - trow * D.tilesC;
  const int r0 = trow * 64, c0 = tcol * 64;

  __shared__ float tile[64][65];
  const int t = threadIdx.x;
  const int sub = t >> 3, oct = t & 7;
  const float Wv = (D.mode == 2) ? *D.Wp : 0.f;

#pragma unroll
  for (int p = 0; p < 2; ++p) {
    const int rl = p * 32 + sub;
    const int cl0 = oct * 8;
    float vv[8];
    if (D.mode == 0) {
      const unsigned short* ip = (const unsigned short*)D.in1 + (size_t)(r0 + rl) * D.C + c0 + cl0;
      U16x8 tmp; tmp.v = *(const uint4*)ip;
#pragma unroll
      for (int i = 0; i < 8; ++i) vv[i] = bf2f(tmp.u[i]);
    } else {
      const float* ip = (const float*)D.in1 + (size_t)(r0 + rl) * D.C + c0 + cl0;
      f32x4 a = *(const f32x4*)ip, b = *(const f32x4*)(ip + 4);
#pragma unroll
      for (int i = 0; i < 4; ++i) { vv[i] = a[i]; vv[4+i] = b[i]; }
      if (D.mode == 2) {
        const float* ip2 = (const float*)D.in2 + (size_t)(r0 + rl) * D.C + c0 + cl0;
        f32x4 c = *(const f32x4*)ip2, d2 = *(const f32x4*)(ip2 + 4);
#pragma unroll
        for (int i = 0; i < 4; ++i) { vv[i] += Wv * c[i]; vv[4+i] += Wv * d2[i]; }
      }
    }
#pragma unroll
    for (int i = 0; i < 8; ++i) tile[cl0 + i][rl] = vv[i];
  }
  __syncthreads();
#pragma unroll
  for (int p = 0; p < 2; ++p) {
    const int cl = p * 32 + sub;
    const int rl0 = oct * 8;
    U16x8 h8, l8;
#pragma unroll
    for (int i = 0; i < 8; ++i) {
      float v = tile[cl][rl0 + i];
      unsigned short h = f2bf(v);
      h8.u[i] = h;
      l8.u[i] = f2bf(v - bf2f(h));
    }
    const size_t o = (size_t)(c0 + cl) * D.R + r0 + rl0;
    *(uint4*)(D.out_hi + o) = h8.v;
    if (D.mode != 0) *(uint4*)(D.out_lo + o) = l8.v;
  }
}

// ---------------------------------------------------------------------------
// batched MFMA GEMM v4: 128x128 tile, BK=64, 4 waves, fused split-bf16.
//   phase 0: stage {Ahi, Bhi, Blo} (48KB) -> Ahi*Bhi + Ahi*Blo  (64 MFMA/wave)
//   phase 1: stage {Alo, Bhi}             -> Alo*Bhi            (32 MFMA/wave)
// Single-buffered, one stage+drain per BK=64 step (32 drains/K=1024-block
// vs 96 in v2/v3). Linear LDS (128B rows) + 3-bit XOR swizzle both sides.
// ---------------------------------------------------------------------------
struct GemmDesc {
  const unsigned short *Ahi, *Alo, *Bhi, *Blo;
  int lda, ldb, nk, accadd;     // nk = K/64 steps per phase
  float* out32a;
  float* out32b;
  const float* addin;
  unsigned short* sp_hi;
  unsigned short* sp_lo;
  const float* heb_in;
  float* heb_out;
};
struct GemmBatch { GemmDesc d[12]; int start[13]; int n; };

__global__ __launch_bounds__(256) void gemm_k(GemmBatch batch) {
  const int bid = blockIdx.x;
  int g = 0;
#pragma unroll
  for (int i = 1; i < 12; ++i)
    if (i < batch.n && bid >= batch.start[i]) g = i;
  GemmDesc D = batch.d[g];
  const int local = bid - batch.start[g];
  const int tm = local >> 3;        // tilesN fixed at 8 (N=1024)
  const int tn = local & 7;

  __shared__ __align__(16) unsigned short As[128 * 64];    // 16 KB
  __shared__ __align__(16) unsigned short BsH[128 * 64];   // 16 KB
  __shared__ __align__(16) unsigned short BsL[128 * 64];   // 16 KB

  const int t = threadIdx.x;
  const int lane = t & 63;
  const int wave = t >> 6;
  const int wr = wave >> 1, wc = wave & 1;
  const int fr = lane & 15, fg = lane >> 4;

  const f32x4 vzero = {0.f, 0.f, 0.f, 0.f};
  f32x4 acc[4][4];
#pragma unroll
  for (int i = 0; i < 4; ++i)
#pragma unroll
    for (int j = 0; j < 4; ++j) acc[i][j] = vzero;

  // staging geometry: rows are 128B; thread t covers rows srow+32q, bytes
  // [scolB, scolB+16) where scolB is the 3-bit XOR pre-swizzled column.
  const int srow = t >> 3;                                   // 0..31
  const int scolB = ((t & 7) << 4) ^ ((srow & 7) << 4);      // bytes in row
  const int scolE = scolB >> 1;                              // elems

  // fragment ds_read byte offsets (s=0 slice; slice 1 = ^0x40)
  int aoff[4], boff[4];
#pragma unroll
  for (int i = 0; i < 4; ++i) {
    const int ra = wr * 64 + i * 16 + fr;
    aoff[i] = ra * 128 + ((fg << 4) ^ ((ra & 7) << 4));
    const int rb = wc * 64 + i * 16 + fr;
    boff[i] = rb * 128 + ((fg << 4) ^ ((rb & 7) << 4));
  }
  const char* Asb = (const char*)As;
  const char* BsHb = (const char*)BsH;
  const char* BsLb = (const char*)BsL;

  const size_t arow = (size_t)(tm * 128 + srow) * D.lda + scolE;
  const size_t brow = (size_t)(tn * 128 + srow) * D.ldb + scolE;
  const size_t astep = (size_t)32 * D.lda;
  const size_t bstep = (size_t)32 * D.ldb;

#pragma unroll 1
  for (int ph = 0; ph < 2; ++ph) {
    const unsigned short* Ap = ph ? D.Alo : D.Ahi;
#pragma unroll 1
    for (int kt = 0; kt < D.nk; ++kt) {
      const int kb = kt << 6;   // k-elem offset
      // ---- stage (12 loads phase0, 8 loads phase1) ----
#pragma unroll
      for (int q = 0; q < 4; ++q) {
        __builtin_amdgcn_global_load_lds(
            (const __attribute__((address_space(1))) void*)(Ap + arow + q * astep + kb),
            (__attribute__((address_space(3))) void*)(As + q * 2048 + wave * 512), 16, 0, 0);
        __builtin_amdgcn_global_load_lds(
            (const __attribute__((address_space(1))) void*)(D.Bhi + brow + q * bstep + kb),
            (__attribute__((address_space(3))) void*)(BsH + q * 2048 + wave * 512), 16, 0, 0);
      }
      if (ph == 0) {
#pragma unroll
        for (int q = 0; q < 4; ++q)
          __builtin_amdgcn_global_load_lds(
              (const __attribute__((address_space(1))) void*)(D.Blo + brow + q * bstep + kb),
              (__attribute__((address_space(3))) void*)(BsL + q * 2048 + wave * 512), 16, 0, 0);
      }
      __syncthreads();           // drain stage, rendezvous
      // ---- compute: 2 k-slices of 32 ----
#pragma unroll
      for (int s = 0; s < 2; ++s) {
        const int sx = s << 6;
        bf16x8 af[4];
#pragma unroll
        for (int i = 0; i < 4; ++i) af[i] = *(const bf16x8*)(Asb + (aoff[i] ^ sx));
#pragma unroll
        for (int j = 0; j < 4; ++j) {
          const bf16x8 bh = *(const bf16x8*)(BsHb + (boff[j] ^ sx));
#pragma unroll
          for (int i = 0; i < 4; ++i)
            acc[i][j] = __builtin_amdgcn_mfma_f32_16x16x32_bf16(af[i], bh, acc[i][j], 0, 0, 0);
          if (ph == 0) {
            const bf16x8 bl = *(const bf16x8*)(BsLb + (boff[j] ^ sx));
#pragma unroll
            for (int i = 0; i < 4; ++i)
              acc[i][j] = __builtin_amdgcn_mfma_f32_16x16x32_bf16(af[i], bl, acc[i][j], 0, 0, 0);
          }
        }
      }
      __syncthreads();           // all reads done before next stage
    }
  }

  const int grb = tm * 128 + wr * 64 + fg * 4;
  const int gcb = tn * 128 + wc * 64 + fr;
#pragma unroll
  for (int i = 0; i < 4; ++i) {
#pragma unroll
    for (int j = 0; j < 4; ++j) {
      const int gc = gcb + j * 16;
#pragma unroll
      for (int r = 0; r < 4; ++r) {
        const int gr = grb + i * 16 + r;
        const size_t idx = (size_t)gr * NDIM + gc;
        const float v = acc[i][j][r];
        if (D.heb_out) {
          D.heb_out[idx] = fminf(fmaxf(D.heb_in[idx] + ALPHA * v, -CLAMPV), CLAMPV);
        } else {
          if (D.out32a) D.out32a[idx] = v;
          if (D.out32b) D.out32b[idx] = D.accadd ? (D.out32b[idx] + v) : v;
          if (D.sp_hi) {
            float rv = v + (D.addin ? D.addin[idx] : 0.f);
            rv = fmaxf(rv, 0.f);
            const unsigned short h = f2bf(rv);
            D.sp_hi[idx] = h;
            D.sp_lo[idx] = f2bf(rv - bf2f(h));
          }
        }
      }
    }
  }
}

// ---------------------------------------------------------------------------
// heb output from up to 8 split-K partials: out = clamp(heb_in + ALPHA*sum)
// ---------------------------------------------------------------------------
struct HebRed { const float* heb_in; float* out; const float* p[8]; int np; };

__global__ __launch_bounds__(256) void hebred_k(HebRed R) {
  const size_t i0 = ((size_t)blockIdx.x * 256 + threadIdx.x) * 4;
  f32x4 s = *(const f32x4*)(R.p[0] + i0);
#pragma unroll
  for (int k = 1; k < 8; ++k)
    if (k < R.np) s += *(const f32x4*)(R.p[k] + i0);
  f32x4 h = *(const f32x4*)(R.heb_in + i0);
  f32x4 o;
#pragma unroll
  for (int i = 0; i < 4; ++i) o[i] = fminf(fmaxf(h[i] + ALPHA * s[i], -CLAMPV), CLAMPV);
  *(f32x4*)(R.out + i0) = o;
}

// ---------------------------------------------------------------------------
__global__ __launch_bounds__(256) void yassm_k(const float* __restrict__ ysum,
                                               float* __restrict__ yout) {
  const int stride = gridDim.x * 256;
  for (int idx = blockIdx.x * 256 + threadIdx.x; idx < BDIM * 1022; idx += stride) {
    const int row = idx / 1022;
    const int col = idx - row * 1022;
    yout[idx] = ysum[(size_t)row * NDIM + col];
  }
}

__global__ __launch_bounds__(256) void tanhcol_k(const float* __restrict__ ysum,
                                                 float* __restrict__ wpart,
                                                 float* __restrict__ dpart) {
  const int r = blockIdx.x * 256 + threadIdx.x;
  const size_t b = (size_t)r * NDIM;
  float tw = tanhf(ysum[b + 1022]);
  float td = tanhf(ysum[b + 1021]);
#pragma unroll
  for (int o = 32; o > 0; o >>= 1) { tw += __shfl_down(tw, o); td += __shfl_down(td, o); }
  __shared__ float s1[4], s2[4];
  const int lane = threadIdx.x & 63, wv = threadIdx.x >> 6;
  if (lane == 0) { s1[wv] = tw; s2[wv] = td; }
  __syncthreads();
  if (threadIdx.x == 0) {
    wpart[blockIdx.x] = s1[0] + s1[1] + s1[2] + s1[3];
    dpart[blockIdx.x] = s2[0] + s2[1] + s2[2] + s2[3];
  }
}

__global__ void finalize_k(const float* __restrict__ wpart, const float* __restrict__ dpart,
                           float* __restrict__ out, int nout) {
  if (threadIdx.x == 0 && blockIdx.x == 0) {
    float s = 0.f, d = 0.f;
    for (int i = 0; i < 16; ++i) { s += wpart[i]; d += dpart[i]; }
    out[nout - 2] = s * (1.f / BDIM);
    out[nout - 1] = d * (1.f / BDIM);
  }
}

// ---------------------------------------------------------------------------
extern "C" void kernel_launch(void* const* d_in, const int* in_sizes, int n_in,
                              void* d_out, int out_size, void* d_ws, size_t ws_size,
                              hipStream_t stream) {
  const float* x = (const float*)d_in[0];
  const float* wbase[6]; const float* hebin[6];
  for (int i = 0; i < 6; ++i) { wbase[i] = (const float*)d_in[1 + i]; hebin[i] = (const float*)d_in[7 + i]; }
  const float* Wp = (const float*)d_in[13];
  float* out = (float*)d_out;
  const size_t YOUT = (size_t)BDIM * 1022;
  float* hebout[6];
  for (int i = 0; i < 6; ++i) hebout[i] = out + YOUT + (size_t)i * 1048576;

  // ---- workspace layout: 200 MiB, lifetime-aliased regions ----
  const size_t E = (size_t)BDIM * NDIM;
  const size_t PAIRB = E * 4;                    // hi+lo bf16 pair (16 MiB)
  const size_t WPAIRB = (size_t)NDIM * NDIM * 4; // weight hi+lo pair (4 MiB)
  const size_t FB = E * 4;                       // f32 buffer (16 MiB)
  const size_t REQUIRED = 7 * PAIRB + 6 * WPAIRB + 4 * FB;

  if (ws_size < REQUIRED) {
    fill_k<<<(out_size + 255) / 256, 256, 0, stream>>>(out, out_size);
    return;
  }

  char* p = (char*)d_ws;
  auto takeB = [&](size_t n) -> char* { char* q = p; p += n; return q; };

  unsigned short* R0 = (unsigned short*)takeB(PAIRB);   // x pair -> h1 pair
  unsigned short* R1 = (unsigned short*)takeB(PAIRB);   // xT pair -> h1T pair
  unsigned short* R2 = (unsigned short*)takeB(PAIRB);   // h0 pair -> fT5 pair
  unsigned short* R3 = (unsigned short*)takeB(PAIRB);   // h0T pair
  unsigned short* R4 = (unsigned short*)takeB(PAIRB);   // fT0 -> fT2 -> h12y parts 0-3
  unsigned short* R5 = (unsigned short*)takeB(PAIRB);   // fT1 -> fT4 -> h12y parts 4-7
  unsigned short* R6 = (unsigned short*)takeB(PAIRB);   // fT3 -> h02y parts -> wpart
  unsigned short* WThi[6]; unsigned short* WTlo[6];
  for (int i = 0; i < 6; ++i) {
    WThi[i] = (unsigned short*)takeB(WPAIRB);
    WTlo[i] = WThi[i] + (size_t)NDIM * NDIM;
  }
  float* F0 = (float*)takeB(FB);   // h0x -> h10
  float* F1 = (float*)takeB(FB);   // h1x -> y1tmp
  float* F2 = (float*)takeB(FB);   // yxtmp -> y0tmp
  float* F3 = (float*)takeB(FB);   // ysum (live to end)

  unsigned short *xhi = R0, *xlo = R0 + E;
  unsigned short *xThi = R1, *xTlo = R1 + E;
  unsigned short *h0hi = R2, *h0lo = R2 + E;
  unsigned short *h0Thi = R3, *h0Tlo = R3 + E;
  float* part = (float*)R4;        // h12y: 8 x 1M f32 spans R4+R5
  float* wpart = (float*)R6; float* dpart = wpart + 64;

  // ---- s1: split x ----
  split_x_k<<<2048, 256, 0, stream>>>(x, xhi, xlo);

  // ---- s2: Weff^T splits (6) + x^T split ----
  {
    TBatch tb{};
    int s = 0;
    for (int i = 0; i < 6; ++i) {
      tb.d[i] = { wbase[i], hebin[i], Wp, WThi[i], WTlo[i], NDIM, NDIM, NDIM / 64, 2 };
      tb.start[i] = s; s += (NDIM / 64) * (NDIM / 64);
    }
    tb.d[6] = { x, nullptr, nullptr, xThi, xTlo, BDIM, NDIM, NDIM / 64, 1 };
    tb.start[6] = s; s += (BDIM / 64) * (NDIM / 64);
    tb.start[7] = s; tb.n = 7;
    transpose_k<<<s, 256, 0, stream>>>(tb);
  }

  auto fwdDesc = [&](const unsigned short* ahi, const unsigned short* alo, int wi) -> GemmDesc {
    GemmDesc d{};
    d.Ahi = ahi; d.Alo = alo; d.Bhi = WThi[wi]; d.Blo = WTlo[wi];
    d.lda = NDIM; d.ldb = NDIM; d.nk = NDIM / 64;
    return d;
  };
  auto hebPart = [&](const unsigned short* ahi, const unsigned short* alo,
                     const unsigned short* bhi, const unsigned short* blo,
                     int koff, int klen, float* partOut) -> GemmDesc {
    GemmDesc d{};
    d.Ahi = ahi + koff; d.Alo = alo + koff;
    d.Bhi = bhi + koff; d.Blo = blo + koff;
    d.lda = BDIM; d.ldb = BDIM; d.nk = klen / 64;
    d.out32a = partOut;
    return d;
  };
  auto hebRed = [&](int hi, const float* q0, const float* q1, const float* q2,
                    const float* q3, const float* q4, const float* q5,
                    const float* q6, const float* q7, int np) {
    HebRed r{};
    r.heb_in = hebin[hi]; r.out = hebout[hi];
    r.p[0]=q0; r.p[1]=q1; r.p[2]=q2; r.p[3]=q3; r.p[4]=q4; r.p[5]=q5; r.p[6]=q6; r.p[7]=q7;
    r.np = np;
    hebred_k<<<1024, 256, 0, stream>>>(r);
  };

  // ---- s3: h0x, h1x, yx  (768 blocks = 3/CU, 32 steps each) ----
  {
    GemmBatch gb{};
    gb.d[0] = fwdDesc(xhi, xlo, 0);
    gb.d[0].out32a = F0; gb.d[0].sp_hi = h0hi; gb.d[0].sp_lo = h0lo;
    gb.d[1] = fwdDesc(xhi, xlo, 1);
    gb.d[1].out32a = F1;
    gb.d[2] = fwdDesc(xhi, xlo, 3);
    gb.d[2].out32a = F2; gb.d[2].out32b = F3; gb.d[2].accadd = 0;
    gb.start[0] = 0; gb.start[1] = 256; gb.start[2] = 512; gb.start[3] = 768;
    gb.n = 3;
    gemm_k<<<768, 256, 0, stream>>>(gb);
  }

  // ---- s4: fT0=h0x^T, fT1=h1x^T, fT3=yx^T (splits); h0T hi/lo ----
  {
    TBatch tb{};
    tb.d[0] = { F0, nullptr, nullptr, R4, R4 + E, BDIM, NDIM, NDIM / 64, 1 };
    tb.d[1] = { F1, nullptr, nullptr, R5, R5 + E, BDIM, NDIM, NDIM / 64, 1 };
    tb.d[2] = { F2, nullptr, nullptr, R6, R6 + E, BDIM, NDIM, NDIM / 64, 1 };
    tb.d[3] = { h0hi, nullptr, nullptr, h0Thi, nullptr, BDIM, NDIM, NDIM / 64, 0 };
    tb.d[4] = { h0lo, nullptr, nullptr, h0Tlo, nullptr, BDIM, NDIM, NDIM / 64, 0 };
    for (int i = 0; i < 6; ++i) tb.start[i] = i * 1024;
    tb.n = 5;
    transpose_k<<<5120, 256, 0, stream>>>(tb);
  }

  // ---- s5: heb{x2h0,x2h1,x2y} 2-way split-K + h10, y0  (896 blocks) ----
  {
    float* px0a = (float*)WThi[0]; float* px0b = hebout[0];
    float* px1a = (float*)WThi[1]; float* px1b = hebout[1];
    float* pxya = (float*)WThi[3]; float* pxyb = hebout[3];
    GemmBatch gb{};
    gb.d[0] = hebPart(xThi, xTlo, R4, R4 + E, 0,    2048, px0a);
    gb.d[1] = hebPart(xThi, xTlo, R4, R4 + E, 2048, 2048, px0b);
    gb.d[2] = hebPart(xThi, xTlo, R5, R5 + E, 0,    2048, px1a);
    gb.d[3] = hebPart(xThi, xTlo, R5, R5 + E, 2048, 2048, px1b);
    gb.d[4] = hebPart(xThi, xTlo, R6, R6 + E, 0,    2048, pxya);
    gb.d[5] = hebPart(xThi, xTlo, R6, R6 + E, 2048, 2048, pxyb);
    gb.d[6] = fwdDesc(h0hi, h0lo, 2);                     // h1_0
    gb.d[6].out32a = F0; gb.d[6].addin = F1; gb.d[6].sp_hi = R0; gb.d[6].sp_lo = R0 + E;
    gb.d[7] = fwdDesc(h0hi, h0lo, 4);                     // y0
    gb.d[7].out32a = F2; gb.d[7].out32b = F3; gb.d[7].accadd = 1;
    for (int i = 0; i < 6; ++i) gb.start[i] = i * 64;
    gb.start[6] = 384; gb.start[7] = 640; gb.start[8] = 896;
    gb.n = 8;
    gemm_k<<<896, 256, 0, stream>>>(gb);
    hebRed(0, px0a, px0b, 0,0,0,0,0,0, 2);
    hebRed(1, px1a, px1b, 0,0,0,0,0,0, 2);
    hebRed(3, pxya, pxyb, 0,0,0,0,0,0, 2);
  }

  // ---- s6: fT2=h10^T, fT4=y0^T (splits); h1T hi/lo into R1 ----
  {
    TBatch tb{};
    tb.d[0] = { F0, nullptr, nullptr, R4, R4 + E, BDIM, NDIM, NDIM / 64, 1 };
    tb.d[1] = { F2, nullptr, nullptr, R5, R5 + E, BDIM, NDIM, NDIM / 64, 1 };
    tb.d[2] = { R0, nullptr, nullptr, R1, nullptr, BDIM, NDIM, NDIM / 64, 0 };
    tb.d[3] = { R0 + E, nullptr, nullptr, R1 + E, nullptr, BDIM, NDIM, NDIM / 64, 0 };
    for (int i = 0; i < 5; ++i) tb.start[i] = i * 1024;
    tb.n = 4;
    transpose_k<<<4096, 256, 0, stream>>>(tb);
  }

  // ---- s7: heb{h02h1,h02y} 4-way split-K + y1  (768 blocks) ----
  {
    float* pa[4] = { (float*)WThi[0], (float*)WThi[1], (float*)WThi[2], (float*)WThi[3] };
    float* pb[4] = { (float*)R6, (float*)R6 + 1048576, (float*)R6 + 2097152, (float*)R6 + 3145728 };
    GemmBatch gb{};
    for (int h = 0; h < 4; ++h) {
      gb.d[h]     = hebPart(h0Thi, h0Tlo, R4, R4 + E, h * 1024, 1024, pa[h]); // h02h1
      gb.d[4 + h] = hebPart(h0Thi, h0Tlo, R5, R5 + E, h * 1024, 1024, pb[h]); // h02y
    }
    gb.d[8] = fwdDesc(R0, R0 + E, 5);                     // y1 (A = h1 pair)
    gb.d[8].out32a = F1; gb.d[8].out32b = F3; gb.d[8].accadd = 1;
    for (int i = 0; i < 8; ++i) gb.start[i] = i * 64;
    gb.start[8] = 512; gb.start[9] = 768;
    gb.n = 9;
    gemm_k<<<768, 256, 0, stream>>>(gb);
    hebRed(2, pa[0], pa[1], pa[2], pa[3], 0,0,0,0, 4);
    hebRed(4, pb[0], pb[1], pb[2], pb[3], 0,0,0,0, 4);
  }

  // ---- s8: fT5 = y1^T split into R2 ----
  {
    TBatch tb{};
    tb.d[0] = { F1, nullptr, nullptr, R2, R2 + E, BDIM, NDIM, NDIM / 64, 1 };
    tb.start[0] = 0; tb.start[1] = 1024; tb.n = 1;
    transpose_k<<<1024, 256, 0, stream>>>(tb);
  }

  // ---- s9: heb_h12y 8-way split-K (512 blocks, 8 steps each) ----
  {
    GemmBatch gb{};
    for (int h = 0; h < 8; ++h)
      gb.d[h] = hebPart(R1, R1 + E, R2, R2 + E, h * 512, 512, part + (size_t)h * 1048576);
    for (int i = 0; i <= 8; ++i) gb.start[i] = i * 64;
    gb.n = 8;
    gemm_k<<<512, 256, 0, stream>>>(gb);
    hebRed(5, part, part + 1048576, part + 2097152, part + 3145728,
           part + 4194304, part + 5242880, part + 6291456, part + 7340032, 8);
  }

  // ---- s10: y assembly, tanh means ----
  yassm_k<<<2048, 256, 0, stream>>>(F3, out);
  tanhcol_k<<<16, 256, 0, stream>>>(F3, wpart, dpart);
  finalize_k<<<1, 64, 0, stream>>>(wpart, dpart, out, out_size);
}